// Round 1
// baseline (195.267 us; speedup 1.0000x reference)
//
#include <hip/hip_runtime.h>
#include <hip/hip_bf16.h>

typedef __hip_bfloat16 bf16;
typedef short bf16x8 __attribute__((ext_vector_type(8)));
typedef float f32x4 __attribute__((ext_vector_type(4)));
typedef unsigned int u32;

static __device__ __forceinline__ float bfu2f(unsigned short u) { return __uint_as_float((u32)u << 16); }
static __device__ __forceinline__ u32 pack2(float a, float b) {
    return (u32)__bfloat16_as_ushort(__float2bfloat16(a))
         | ((u32)__bfloat16_as_ushort(__float2bfloat16(b)) << 16);
}
static __device__ __forceinline__ float wave_sum(float v) {
    #pragma unroll
    for (int off = 32; off > 0; off >>= 1) v += __shfl_xor(v, off);
    return v;
}

// async global->LDS 16B copy (wave-uniform LDS base + lane*16 by HW).
static __device__ __forceinline__ void gll16(const bf16* g, bf16* l) {
    __builtin_amdgcn_global_load_lds((const __attribute__((address_space(1))) void*)g,
                                     (__attribute__((address_space(3))) void*)l,
                                     16, 0, 0);
}

// ---------------------------------------------------------------------------
// Fused fp32->bf16 cast of Q, K, Wq, Wk, Wv, Wo. 4096 elems/block, 16/thread.
// ---------------------------------------------------------------------------
__global__ __launch_bounds__(256) void castall(const float* __restrict__ Q,  const float* __restrict__ K,
                                               const float* __restrict__ Wq, const float* __restrict__ Wk,
                                               const float* __restrict__ Wv, const float* __restrict__ Wo,
                                               bf16* __restrict__ dQ,  bf16* __restrict__ dK,
                                               bf16* __restrict__ dWq, bf16* __restrict__ dWk,
                                               bf16* __restrict__ dWv, bf16* __restrict__ dWo)
{
    const int b = blockIdx.x;
    const float* src; bf16* dst; size_t off;
    if (b < 1024)      { src = Q;  dst = dQ;  off = (size_t)b * 4096; }
    else if (b < 2048) { src = K;  dst = dK;  off = (size_t)(b - 1024) * 4096; }
    else {
        const int wb = b - 2048, wi = wb >> 6;
        off = (size_t)(wb & 63) * 4096;
        src = wi == 0 ? Wq : wi == 1 ? Wk : wi == 2 ? Wv : Wo;
        dst = wi == 0 ? dWq : wi == 1 ? dWk : wi == 2 ? dWv : dWo;
    }
    const size_t p = off + threadIdx.x * 16;
    const float4 v0 = *(const float4*)(src + p);
    const float4 v1 = *(const float4*)(src + p + 4);
    const float4 v2 = *(const float4*)(src + p + 8);
    const float4 v3 = *(const float4*)(src + p + 12);
    uint4 o0, o1;
    o0.x = pack2(v0.x, v0.y); o0.y = pack2(v0.z, v0.w);
    o0.z = pack2(v1.x, v1.y); o0.w = pack2(v1.z, v1.w);
    o1.x = pack2(v2.x, v2.y); o1.y = pack2(v2.z, v2.w);
    o1.z = pack2(v3.x, v3.y); o1.w = pack2(v3.z, v3.w);
    *(uint4*)(dst + p)     = o0;
    *(uint4*)(dst + p + 8) = o1;
}

// ---------------------------------------------------------------------------
// Fused QKV projection GEMM (NT), 128x128 tiles, BK=64 single-buffered
// gll16 staging (8 iters, 2 barriers each), unpadded [128][64] LDS with
// granule swizzle LDS[row][g] = glob[row][g ^ (row&7)].
// Q/K-proj compute C^T (operand-swapped) so a lane's 4 acc regs are 4
// consecutive d -> uint2 stores; V-proj computes C normally (regs = 4
// consecutive n, contiguous in the [b,h,d,n] layout). Grid (64, 12).
// ---------------------------------------------------------------------------
__global__ __launch_bounds__(256) void gemm_qkv(const bf16* __restrict__ Aq, const bf16* __restrict__ Ak,
                                                const bf16* __restrict__ Wq, const bf16* __restrict__ Wk,
                                                const bf16* __restrict__ Wv,
                                                const float* __restrict__ bq, const float* __restrict__ bk,
                                                const float* __restrict__ bv,
                                                bf16* __restrict__ oQ, bf16* __restrict__ oK,
                                                bf16* __restrict__ oV)
{
    __shared__ bf16 Xs[128 * 64];
    __shared__ bf16 Ws[128 * 64];

    const int tid = threadIdx.x, lane = tid & 63, wave = tid >> 6;
    const int yy = blockIdx.y, wi = yy >> 2;
    const bf16* A     = wi == 0 ? Aq : Ak;
    const bf16* W     = wi == 0 ? Wq : wi == 1 ? Wk : Wv;
    const float* bias = wi == 0 ? bq : wi == 1 ? bk : bv;
    bf16* out         = wi == 0 ? oQ : wi == 1 ? oK : oV;
    const bool vmode  = (wi == 2);
    const int bm = blockIdx.x * 128;
    const int bn = (yy & 3) * 128;

    // staging: slot s = tid + 256c -> row (tid>>3)+32c, lds granule tid&7,
    // source granule (tid&7)^((tid>>3)&7)
    const int srow = tid >> 3;
    const int sg8  = (((tid & 7) ^ (srow & 7)) * 8);
    const int wm = (wave >> 1) * 64, wn = (wave & 1) * 64;
    const int fr = lane & 15, fq = lane >> 4;

    f32x4 acc[4][4] = {};
    const bf16* Ap = A + (size_t)(bm + srow) * 512 + sg8;
    const bf16* Wp = W + (size_t)(bn + srow) * 512 + sg8;
    const int ld = 8 * tid;

    for (int k0 = 0; k0 < 512; k0 += 64) {
        __syncthreads();
        #pragma unroll
        for (int c = 0; c < 4; c++) {
            gll16(Ap + k0 + (size_t)(32 * c) * 512, Xs + ld + 2048 * c);
            gll16(Wp + k0 + (size_t)(32 * c) * 512, Ws + ld + 2048 * c);
        }
        __syncthreads();

        #pragma unroll
        for (int c2 = 0; c2 < 2; c2++) {
            bf16x8 fx[4], fw[4];
            #pragma unroll
            for (int i = 0; i < 4; i++) {
                const int rx = wm + 16 * i + fr;
                const int rw = wn + 16 * i + fr;
                fx[i] = *(const bf16x8*)(&Xs[rx * 64 + (((c2 * 4 + fq) ^ (rx & 7)) * 8)]);
                fw[i] = *(const bf16x8*)(&Ws[rw * 64 + (((c2 * 4 + fq) ^ (rw & 7)) * 8)]);
            }
            if (vmode) {
                #pragma unroll
                for (int i = 0; i < 4; i++)
                    #pragma unroll
                    for (int j = 0; j < 4; j++)
                        acc[i][j] = __builtin_amdgcn_mfma_f32_16x16x32_bf16(fx[i], fw[j], acc[i][j], 0, 0, 0);
            } else {
                #pragma unroll
                for (int i = 0; i < 4; i++)
                    #pragma unroll
                    for (int j = 0; j < 4; j++)
                        acc[i][j] = __builtin_amdgcn_mfma_f32_16x16x32_bf16(fw[i], fx[j], acc[i][j], 0, 0, 0);
            }
        }
    }

    if (!vmode) {
        // C^T: acc[i][j] row = weight-col (d_full), col = data-row (n).
        // lane regs r -> 4 consecutive d. out[((b*8+h)*1024+n)*64+d]
        #pragma unroll
        for (int i = 0; i < 4; i++) {
            const int colb = bn + wn + 16 * i + 4 * fq;   // d_full base (mult of 4)
            const float4 b4 = *(const float4*)(bias + colb);
            const int h = colb >> 6, d0 = colb & 63;
            #pragma unroll
            for (int j = 0; j < 4; j++) {
                const int n = bm + wm + 16 * j + fr;
                const int b = n >> 10, nn = n & 1023;
                uint2 pk;
                pk.x = pack2(acc[i][j][0] + b4.x, acc[i][j][1] + b4.y);
                pk.y = pack2(acc[i][j][2] + b4.z, acc[i][j][3] + b4.w);
                *(uint2*)(out + ((size_t)(b * 8 + h) * 1024 + nn) * 64 + d0) = pk;
            }
        }
    } else {
        // C: acc[i][j] row = data-row (n), col = weight-col. regs = 4 consec n.
        // out[((b*8+h)*64+d)*1024+n]
        #pragma unroll
        for (int i = 0; i < 4; i++) {
            const int n0 = bm + wm + 16 * i + 4 * fq;     // mult of 4
            const int b = n0 >> 10, nn = n0 & 1023;
            #pragma unroll
            for (int j = 0; j < 4; j++) {
                const int col = bn + wn + 16 * j + fr;
                const float bv2 = bias[col];
                const int h = col >> 6, d = col & 63;
                uint2 pk;
                pk.x = pack2(acc[i][j][0] + bv2, acc[i][j][1] + bv2);
                pk.y = pack2(acc[i][j][2] + bv2, acc[i][j][3] + bv2);
                *(uint2*)(out + ((size_t)(b * 8 + h) * 64 + d) * 1024 + nn) = pk;
            }
        }
    }
}

// ---------------------------------------------------------------------------
// O-projection GEMM (NT), 64x128 tiles, BK=64 single-buffered gll16 staging.
// Operand-swapped (C^T) -> uint2 stores along columns. Grid (128, 4).
// Waves split the 128 weight cols (wave tile: 32 cols x 64 rows).
// ---------------------------------------------------------------------------
__global__ __launch_bounds__(256) void gemm_o(const bf16* __restrict__ A,
                                              const bf16* __restrict__ W,
                                              const float* __restrict__ bias,
                                              bf16* __restrict__ out)
{
    __shared__ bf16 Xs[64 * 64];
    __shared__ bf16 Ws[128 * 64];

    const int tid = threadIdx.x, lane = tid & 63, wave = tid >> 6;
    const int bm = blockIdx.x * 64;
    const int bn = blockIdx.y * 128;

    const int srow = tid >> 3;
    const int sg8  = (((tid & 7) ^ (srow & 7)) * 8);
    const int wn = wave * 32;
    const int fr = lane & 15, fq = lane >> 4;

    f32x4 acc[2][4] = {};
    const bf16* Ap = A + (size_t)(bm + srow) * 512 + sg8;
    const bf16* Wp = W + (size_t)(bn + srow) * 512 + sg8;
    const int ld = 8 * tid;

    for (int k0 = 0; k0 < 512; k0 += 64) {
        __syncthreads();
        #pragma unroll
        for (int c = 0; c < 2; c++)
            gll16(Ap + k0 + (size_t)(32 * c) * 512, Xs + ld + 2048 * c);
        #pragma unroll
        for (int c = 0; c < 4; c++)
            gll16(Wp + k0 + (size_t)(32 * c) * 512, Ws + ld + 2048 * c);
        __syncthreads();

        #pragma unroll
        for (int c2 = 0; c2 < 2; c2++) {
            bf16x8 fx[4], fw[2];
            #pragma unroll
            for (int j = 0; j < 4; j++) {
                const int rx = 16 * j + fr;
                fx[j] = *(const bf16x8*)(&Xs[rx * 64 + (((c2 * 4 + fq) ^ (rx & 7)) * 8)]);
            }
            #pragma unroll
            for (int i = 0; i < 2; i++) {
                const int rw = wn + 16 * i + fr;
                fw[i] = *(const bf16x8*)(&Ws[rw * 64 + (((c2 * 4 + fq) ^ (rw & 7)) * 8)]);
            }
            #pragma unroll
            for (int i = 0; i < 2; i++)
                #pragma unroll
                for (int j = 0; j < 4; j++)
                    acc[i][j] = __builtin_amdgcn_mfma_f32_16x16x32_bf16(fw[i], fx[j], acc[i][j], 0, 0, 0);
        }
    }

    #pragma unroll
    for (int i = 0; i < 2; i++) {
        const int colb = bn + wn + 16 * i + 4 * fq;
        const float4 b4 = *(const float4*)(bias + colb);
        #pragma unroll
        for (int j = 0; j < 4; j++) {
            const int row = bm + 16 * j + fr;
            uint2 pk;
            pk.x = pack2(acc[i][j][0] + b4.x, acc[i][j][1] + b4.y);
            pk.y = pack2(acc[i][j][2] + b4.z, acc[i][j][3] + b4.w);
            *(uint2*)(out + (size_t)row * 512 + colb) = pk;
        }
    }
}

// ---------------------------------------------------------------------------
// MFMA flash attention — S^T form, fixed-max softmax, 32 q-rows per wave.
// Round-N changes vs previous:
//   * V fragments read DIRECTLY from global (L2-resident, [b,h,d,m] layout is
//     contiguous along m) — eliminates Vs staging + Vs LDS reads (−36% LDS
//     traffic). Loads issued at iter top so QK^T+softmax hides L2 latency.
//   * K staging double-buffered (Ks[2]) with counted vmcnt: issue next K tile
//     + this iter's V loads, then s_waitcnt vmcnt(10) (drains only previous
//     K gll16s, keeps the 10 new ops in flight) + raw s_barrier.
//   * s_setprio(1) around MFMA bursts (T5).
// LDS total unchanged (2x8KB Ks + 18KB Ps = 34KB) -> occupancy unchanged.
// Qh [b,h,n,64], Kh [b,h,m,64], VhT [b,h,d,m]. Flat grid 512, 4 waves.
// ---------------------------------------------------------------------------
__global__ __launch_bounds__(256) void attn_mfma(const bf16* __restrict__ Qh,
                                                 const bf16* __restrict__ Kh,
                                                 const bf16* __restrict__ VhT,
                                                 bf16* __restrict__ Oc)
{
    __shared__ bf16 Ks[2][64 * 64];
    __shared__ bf16 Ps[4][2][16 * 72];

    const int tid = threadIdx.x, lane = tid & 63, w = tid >> 6;
    const int id = blockIdx.x;
    const int bh = (id & 7) * 8 + (id >> 6);       // XCD-local bh grouping
    const int wq = ((id >> 3) & 7) * 128 + w * 32; // wave's first q-row

    const bf16* Qb = Qh  + ((size_t)bh * 1024 + wq) * 64;
    const bf16* Kb = Kh  + (size_t)bh * 1024 * 64;
    const bf16* Vb = VhT + (size_t)bh * 64 * 1024;

    const int fl = lane & 15, fq = lane >> 4;
    const int flk = fl & 7;
    const int gA = (fq ^ flk) * 8;
    const int gB = ((4 | fq) ^ flk) * 8;

    bf16x8 qf[2][2];
    #pragma unroll
    for (int t = 0; t < 2; t++) {
        qf[t][0] = *(const bf16x8*)(Qb + (16 * t + fl) * 64 + fq * 8);
        qf[t][1] = *(const bf16x8*)(Qb + (16 * t + fl) * 64 + 32 + fq * 8);
    }

    f32x4 o[2][4] = {};
    float lsum[2] = {0.f, 0.f};
    const float sc2 = 0.04419417382415922f * 1.4426950408889634f; // /sqrt(512)*log2e

    const int srow = tid >> 3;
    const int sg8  = (((tid & 7) ^ (srow & 7)) * 8);
    const bf16* KbR = Kb + (size_t)srow * 64 + sg8;
    const int ld = 8 * tid;

    // per-lane V base: row d = 16*jd + fl, m-cols fq*8 (+32) within tile
    const bf16* VbL = Vb + (size_t)fl * 1024 + fq * 8;

    // prologue: stage K tile 0 into buffer 0
    gll16(KbR,           &Ks[0][0] + ld);
    gll16(KbR + 32 * 64, &Ks[0][0] + 2048 + ld);

    #pragma unroll 1
    for (int kt = 0; kt < 16; kt++) {
        const int m0 = kt * 64;
        const bf16* Ksc = &Ks[kt & 1][0];

        // V fragments for THIS iter, direct from global (L2). Latency hides
        // under QK^T + softmax; compiler inserts the wait before PV use.
        bf16x8 vf[4][2];
        #pragma unroll
        for (int jd = 0; jd < 4; jd++) {
            const bf16* vp = VbL + (size_t)(16 * jd) * 1024 + m0;
            vf[jd][0] = *(const bf16x8*)(vp);
            vf[jd][1] = *(const bf16x8*)(vp + 32);
        }

        // issue NEXT K tile into the other buffer, then wait only for the
        // PREVIOUS tile's 2 gll16s (8 V loads + 2 gll16 stay in flight).
        if (kt < 15) {
            bf16* Kn = &Ks[(kt + 1) & 1][0];
            gll16(KbR + (size_t)(m0 + 64) * 64, Kn + ld);
            gll16(KbR + (size_t)(m0 + 96) * 64, Kn + 2048 + ld);
            asm volatile("s_waitcnt vmcnt(10)" ::: "memory");
        } else {
            asm volatile("s_waitcnt vmcnt(8)" ::: "memory");
        }
        __builtin_amdgcn_s_barrier();   // Ks[kt&1] staged block-wide

        // K fragments once, reused by both q-tiles
        bf16x8 kf[4][2];
        #pragma unroll
        for (int tm = 0; tm < 4; tm++) {
            kf[tm][0] = *(const bf16x8*)(&Ksc[(16 * tm + fl) * 64 + gA]);
            kf[tm][1] = *(const bf16x8*)(&Ksc[(16 * tm + fl) * 64 + gB]);
        }

        #pragma unroll
        for (int t = 0; t < 2; t++) {
            f32x4 st[4] = {};
            __builtin_amdgcn_s_setprio(1);
            #pragma unroll
            for (int tm = 0; tm < 4; tm++) {
                st[tm] = __builtin_amdgcn_mfma_f32_16x16x32_bf16(kf[tm][0], qf[t][0], st[tm], 0, 0, 0);
                st[tm] = __builtin_amdgcn_mfma_f32_16x16x32_bf16(kf[tm][1], qf[t][1], st[tm], 0, 0, 0);
            }
            __builtin_amdgcn_s_setprio(0);
            #pragma unroll
            for (int tm = 0; tm < 4; tm++) {
                float p0 = __builtin_amdgcn_exp2f(st[tm][0] * sc2);
                float p1 = __builtin_amdgcn_exp2f(st[tm][1] * sc2);
                float p2 = __builtin_amdgcn_exp2f(st[tm][2] * sc2);
                float p3 = __builtin_amdgcn_exp2f(st[tm][3] * sc2);
                lsum[t] += (p0 + p1) + (p2 + p3);
                uint2 pk;
                pk.x = pack2(p0, p1);
                pk.y = pack2(p2, p3);
                *(uint2*)(&Ps[w][t][fl * 72 + 16 * tm + fq * 4]) = pk;
            }
        }

        #pragma unroll
        for (int t = 0; t < 2; t++) {
            bf16x8 pf0 = *(const bf16x8*)(&Ps[w][t][fl * 72 + fq * 8]);
            bf16x8 pf1 = *(const bf16x8*)(&Ps[w][t][fl * 72 + 32 + fq * 8]);
            __builtin_amdgcn_s_setprio(1);
            #pragma unroll
            for (int jd = 0; jd < 4; jd++) {
                o[t][jd] = __builtin_amdgcn_mfma_f32_16x16x32_bf16(vf[jd][0], pf0, o[t][jd], 0, 0, 0);
                o[t][jd] = __builtin_amdgcn_mfma_f32_16x16x32_bf16(vf[jd][1], pf1, o[t][jd], 0, 0, 0);
            }
            __builtin_amdgcn_s_setprio(0);
        }
        __builtin_amdgcn_s_barrier();   // all waves done reading Ks[kt&1]
    }

    const int b = bh >> 3, h = bh & 7;
    #pragma unroll
    for (int t = 0; t < 2; t++) {
        float ls = lsum[t];
        ls += __shfl_xor(ls, 16);
        ls += __shfl_xor(ls, 32);
        const float linv = 1.f / ls;
        const size_t obase = ((size_t)(b * 1024 + wq + 16 * t + fl)) * 512 + h * 64;
        #pragma unroll
        for (int jd = 0; jd < 4; jd++) {
            const ushort4 qr = *(const ushort4*)(Qb + (16 * t + fl) * 64 + 16 * jd + fq * 4);
            uint2 w2;
            w2.x = pack2(o[t][jd][0] * linv + bfu2f(qr.x), o[t][jd][1] * linv + bfu2f(qr.y));
            w2.y = pack2(o[t][jd][2] * linv + bfu2f(qr.z), o[t][jd][3] * linv + bfu2f(qr.w));
            *(uint2*)(&Oc[obase + 16 * jd + fq * 4]) = w2;
        }
    }
}

// ---------------------------------------------------------------------------
// LayerNorm over rows of 512 — wave/row, 8 consecutive elems/lane.
// ---------------------------------------------------------------------------
__global__ __launch_bounds__(256) void ln0(const bf16* __restrict__ X,
                                           const float* __restrict__ g,
                                           const float* __restrict__ be,
                                           bf16* __restrict__ Y)
{
    const int lane = threadIdx.x & 63;
    const int row = blockIdx.x * 4 + (threadIdx.x >> 6);
    const size_t base = (size_t)row * 512 + lane * 8;
    const bf16x8 xv = *(const bf16x8*)(X + base);
    float x[8];
    #pragma unroll
    for (int j = 0; j < 8; j++) x[j] = bfu2f((unsigned short)xv[j]);
    float s = 0.f, s2 = 0.f;
    #pragma unroll
    for (int j = 0; j < 8; j++) { s += x[j]; s2 += x[j] * x[j]; }
    s = wave_sum(s); s2 = wave_sum(s2);
    const float mean = s * (1.f / 512.f);
    const float var = s2 * (1.f / 512.f) - mean * mean;
    const float rs = rsqrtf(fmaxf(var, 0.f) + 1e-5f);
    const float4 gv0 = *(const float4*)(g + lane * 8);
    const float4 gv1 = *(const float4*)(g + lane * 8 + 4);
    const float4 bv0 = *(const float4*)(be + lane * 8);
    const float4 bv1 = *(const float4*)(be + lane * 8 + 4);
    uint4 ov;
    ov.x = pack2((x[0]-mean)*rs*gv0.x + bv0.x, (x[1]-mean)*rs*gv0.y + bv0.y);
    ov.y = pack2((x[2]-mean)*rs*gv0.z + bv0.z, (x[3]-mean)*rs*gv0.w + bv0.w);
    ov.z = pack2((x[4]-mean)*rs*gv1.x + bv1.x, (x[5]-mean)*rs*gv1.y + bv1.y);
    ov.w = pack2((x[6]-mean)*rs*gv1.z + bv1.z, (x[7]-mean)*rs*gv1.w + bv1.w);
    *(uint4*)(Y + base) = ov;
}

__global__ __launch_bounds__(256) void ln1(const bf16* __restrict__ X,
                                           const bf16* __restrict__ R,
                                           const float* __restrict__ g,
                                           const float* __restrict__ be,
                                           float* __restrict__ Y)
{
    const int lane = threadIdx.x & 63;
    const int row = blockIdx.x * 4 + (threadIdx.x >> 6);
    const size_t base = (size_t)row * 512 + lane * 8;
    const bf16x8 xv = *(const bf16x8*)(X + base);
    const bf16x8 rv = *(const bf16x8*)(R + base);
    float x[8];
    #pragma unroll
    for (int j = 0; j < 8; j++)
        x[j] = bfu2f((unsigned short)rv[j]) + fmaxf(bfu2f((unsigned short)xv[j]), 0.f);
    float s = 0.f, s2 = 0.f;
    #pragma unroll
    for (int j = 0; j < 8; j++) { s += x[j]; s2 += x[j] * x[j]; }
    s = wave_sum(s); s2 = wave_sum(s2);
    const float mean = s * (1.f / 512.f);
    const float var = s2 * (1.f / 512.f) - mean * mean;
    const float rs = rsqrtf(fmaxf(var, 0.f) + 1e-5f);
    const float4 gv0 = *(const float4*)(g + lane * 8);
    const float4 gv1 = *(const float4*)(g + lane * 8 + 4);
    const float4 bv0 = *(const float4*)(be + lane * 8);
    const float4 bv1 = *(const float4*)(be + lane * 8 + 4);
    float4 y0, y1;
    y0.x = (x[0]-mean)*rs*gv0.x + bv0.x; y0.y = (x[1]-mean)*rs*gv0.y + bv0.y;
    y0.z = (x[2]-mean)*rs*gv0.z + bv0.z; y0.w = (x[3]-mean)*rs*gv0.w + bv0.w;
    y1.x = (x[4]-mean)*rs*gv1.x + bv1.x; y1.y = (x[5]-mean)*rs*gv1.y + bv1.y;
    y1.z = (x[6]-mean)*rs*gv1.z + bv1.z; y1.w = (x[7]-mean)*rs*gv1.w + bv1.w;
    *(float4*)(Y + base)     = y0;
    *(float4*)(Y + base + 4) = y1;
}

// ---------------------------------------------------------------------------
extern "C" void kernel_launch(void* const* d_in, const int* in_sizes, int n_in,
                              void* d_out, int out_size, void* d_ws, size_t ws_size,
                              hipStream_t stream)
{
    const float* Q   = (const float*)d_in[0];
    const float* K   = (const float*)d_in[1];
    const float* Wq  = (const float*)d_in[2];
    const float* bq  = (const float*)d_in[3];
    const float* Wk  = (const float*)d_in[4];
    const float* bk  = (const float*)d_in[5];
    const float* Wv  = (const float*)d_in[6];
    const float* bv  = (const float*)d_in[7];
    const float* Wo  = (const float*)d_in[8];
    const float* bo  = (const float*)d_in[9];
    const float* g0  = (const float*)d_in[10];
    const float* be0 = (const float*)d_in[11];
    const float* g1  = (const float*)d_in[12];
    const float* be1 = (const float*)d_in[13];
    float* out = (float*)d_out;

    const size_t NQK = (size_t)8 * 1024 * 512;  // 4M
    const size_t NW  = (size_t)512 * 512;       // 256K
    bf16* ws   = (bf16*)d_ws;
    bf16* cQ   = ws;
    bf16* cK   = cQ + NQK;
    bf16* cWq  = cK + NQK;
    bf16* cWk  = cWq + NW;
    bf16* cWv  = cWk + NW;
    bf16* cWo  = cWv + NW;
    bf16* pQh  = cWo + NW;           // [b,h,n,d]
    bf16* pKh  = pQh + NQK;          // [b,h,m,d]
    bf16* pVhT = pKh + NQK;          // [b,h,d,m]
    bf16* pOc  = (bf16*)d_out;       // attn output staged in d_out
    bf16* pO1  = pKh;                // Kh dead after attn
    bf16* pTmp = pQh;                // Qh dead after attn

    castall<<<2304, 256, 0, stream>>>(Q, K, Wq, Wk, Wv, Wo, cQ, cK, cWq, cWk, cWv, cWo);
    gemm_qkv<<<dim3(64, 12), 256, 0, stream>>>(cQ, cK, cWq, cWk, cWv, bq, bk, bv, pQh, pKh, pVhT);
    attn_mfma<<<512, 256, 0, stream>>>(pQh, pKh, pVhT, pOc);
    ln0<<<2048, 256, 0, stream>>>(pOc, g0, be0, pO1);
    gemm_o<<<dim3(128, 4), 256, 0, stream>>>(pO1, cWo, bo, pTmp);
    ln1<<<2048, 256, 0, stream>>>(pTmp, pO1, g1, be1, out);
}

// Round 2
// 187.630 us; speedup vs baseline: 1.0407x; 1.0407x over previous
//
#include <hip/hip_runtime.h>
#include <hip/hip_bf16.h>

typedef __hip_bfloat16 bf16;
typedef short bf16x8 __attribute__((ext_vector_type(8)));
typedef float f32x4 __attribute__((ext_vector_type(4)));
typedef unsigned int u32;

static __device__ __forceinline__ float bfu2f(unsigned short u) { return __uint_as_float((u32)u << 16); }
static __device__ __forceinline__ u32 pack2(float a, float b) {
    return (u32)__bfloat16_as_ushort(__float2bfloat16(a))
         | ((u32)__bfloat16_as_ushort(__float2bfloat16(b)) << 16);
}
static __device__ __forceinline__ float wave_sum(float v) {
    #pragma unroll
    for (int off = 32; off > 0; off >>= 1) v += __shfl_xor(v, off);
    return v;
}

// async global->LDS 16B copy (wave-uniform LDS base + lane*16 by HW).
static __device__ __forceinline__ void gll16(const bf16* g, bf16* l) {
    __builtin_amdgcn_global_load_lds((const __attribute__((address_space(1))) void*)g,
                                     (__attribute__((address_space(3))) void*)l,
                                     16, 0, 0);
}

// ---------------------------------------------------------------------------
// Fused fp32->bf16 cast of Q, K, Wq, Wk, Wv, Wo. 4096 elems/block, 16/thread.
// ---------------------------------------------------------------------------
__global__ __launch_bounds__(256) void castall(const float* __restrict__ Q,  const float* __restrict__ K,
                                               const float* __restrict__ Wq, const float* __restrict__ Wk,
                                               const float* __restrict__ Wv, const float* __restrict__ Wo,
                                               bf16* __restrict__ dQ,  bf16* __restrict__ dK,
                                               bf16* __restrict__ dWq, bf16* __restrict__ dWk,
                                               bf16* __restrict__ dWv, bf16* __restrict__ dWo)
{
    const int b = blockIdx.x;
    const float* src; bf16* dst; size_t off;
    if (b < 1024)      { src = Q;  dst = dQ;  off = (size_t)b * 4096; }
    else if (b < 2048) { src = K;  dst = dK;  off = (size_t)(b - 1024) * 4096; }
    else {
        const int wb = b - 2048, wi = wb >> 6;
        off = (size_t)(wb & 63) * 4096;
        src = wi == 0 ? Wq : wi == 1 ? Wk : wi == 2 ? Wv : Wo;
        dst = wi == 0 ? dWq : wi == 1 ? dWk : wi == 2 ? dWv : dWo;
    }
    const size_t p = off + threadIdx.x * 16;
    const float4 v0 = *(const float4*)(src + p);
    const float4 v1 = *(const float4*)(src + p + 4);
    const float4 v2 = *(const float4*)(src + p + 8);
    const float4 v3 = *(const float4*)(src + p + 12);
    uint4 o0, o1;
    o0.x = pack2(v0.x, v0.y); o0.y = pack2(v0.z, v0.w);
    o0.z = pack2(v1.x, v1.y); o0.w = pack2(v1.z, v1.w);
    o1.x = pack2(v2.x, v2.y); o1.y = pack2(v2.z, v2.w);
    o1.z = pack2(v3.x, v3.y); o1.w = pack2(v3.z, v3.w);
    *(uint4*)(dst + p)     = o0;
    *(uint4*)(dst + p + 8) = o1;
}

// ---------------------------------------------------------------------------
// Fused QKV projection GEMM (NT), 128x128 tiles, BK=64 single-buffered
// gll16 staging (8 iters, 2 barriers each), unpadded [128][64] LDS with
// granule swizzle LDS[row][g] = glob[row][g ^ (row&7)].
// Q/K-proj compute C^T (operand-swapped) so a lane's 4 acc regs are 4
// consecutive d -> uint2 stores; V-proj computes C normally (regs = 4
// consecutive n, contiguous in the [b,h,d,n] layout). Grid (64, 12).
// ---------------------------------------------------------------------------
__global__ __launch_bounds__(256) void gemm_qkv(const bf16* __restrict__ Aq, const bf16* __restrict__ Ak,
                                                const bf16* __restrict__ Wq, const bf16* __restrict__ Wk,
                                                const bf16* __restrict__ Wv,
                                                const float* __restrict__ bq, const float* __restrict__ bk,
                                                const float* __restrict__ bv,
                                                bf16* __restrict__ oQ, bf16* __restrict__ oK,
                                                bf16* __restrict__ oV)
{
    __shared__ bf16 Xs[128 * 64];
    __shared__ bf16 Ws[128 * 64];

    const int tid = threadIdx.x, lane = tid & 63, wave = tid >> 6;
    const int yy = blockIdx.y, wi = yy >> 2;
    const bf16* A     = wi == 0 ? Aq : Ak;
    const bf16* W     = wi == 0 ? Wq : wi == 1 ? Wk : Wv;
    const float* bias = wi == 0 ? bq : wi == 1 ? bk : bv;
    bf16* out         = wi == 0 ? oQ : wi == 1 ? oK : oV;
    const bool vmode  = (wi == 2);
    const int bm = blockIdx.x * 128;
    const int bn = (yy & 3) * 128;

    // staging: slot s = tid + 256c -> row (tid>>3)+32c, lds granule tid&7,
    // source granule (tid&7)^((tid>>3)&7)
    const int srow = tid >> 3;
    const int sg8  = (((tid & 7) ^ (srow & 7)) * 8);
    const int wm = (wave >> 1) * 64, wn = (wave & 1) * 64;
    const int fr = lane & 15, fq = lane >> 4;

    f32x4 acc[4][4] = {};
    const bf16* Ap = A + (size_t)(bm + srow) * 512 + sg8;
    const bf16* Wp = W + (size_t)(bn + srow) * 512 + sg8;
    const int ld = 8 * tid;

    for (int k0 = 0; k0 < 512; k0 += 64) {
        __syncthreads();
        #pragma unroll
        for (int c = 0; c < 4; c++) {
            gll16(Ap + k0 + (size_t)(32 * c) * 512, Xs + ld + 2048 * c);
            gll16(Wp + k0 + (size_t)(32 * c) * 512, Ws + ld + 2048 * c);
        }
        __syncthreads();

        #pragma unroll
        for (int c2 = 0; c2 < 2; c2++) {
            bf16x8 fx[4], fw[4];
            #pragma unroll
            for (int i = 0; i < 4; i++) {
                const int rx = wm + 16 * i + fr;
                const int rw = wn + 16 * i + fr;
                fx[i] = *(const bf16x8*)(&Xs[rx * 64 + (((c2 * 4 + fq) ^ (rx & 7)) * 8)]);
                fw[i] = *(const bf16x8*)(&Ws[rw * 64 + (((c2 * 4 + fq) ^ (rw & 7)) * 8)]);
            }
            if (vmode) {
                #pragma unroll
                for (int i = 0; i < 4; i++)
                    #pragma unroll
                    for (int j = 0; j < 4; j++)
                        acc[i][j] = __builtin_amdgcn_mfma_f32_16x16x32_bf16(fx[i], fw[j], acc[i][j], 0, 0, 0);
            } else {
                #pragma unroll
                for (int i = 0; i < 4; i++)
                    #pragma unroll
                    for (int j = 0; j < 4; j++)
                        acc[i][j] = __builtin_amdgcn_mfma_f32_16x16x32_bf16(fw[i], fx[j], acc[i][j], 0, 0, 0);
            }
        }
    }

    if (!vmode) {
        // C^T: acc[i][j] row = weight-col (d_full), col = data-row (n).
        // lane regs r -> 4 consecutive d. out[((b*8+h)*1024+n)*64+d]
        #pragma unroll
        for (int i = 0; i < 4; i++) {
            const int colb = bn + wn + 16 * i + 4 * fq;   // d_full base (mult of 4)
            const float4 b4 = *(const float4*)(bias + colb);
            const int h = colb >> 6, d0 = colb & 63;
            #pragma unroll
            for (int j = 0; j < 4; j++) {
                const int n = bm + wm + 16 * j + fr;
                const int b = n >> 10, nn = n & 1023;
                uint2 pk;
                pk.x = pack2(acc[i][j][0] + b4.x, acc[i][j][1] + b4.y);
                pk.y = pack2(acc[i][j][2] + b4.z, acc[i][j][3] + b4.w);
                *(uint2*)(out + ((size_t)(b * 8 + h) * 1024 + nn) * 64 + d0) = pk;
            }
        }
    } else {
        // C: acc[i][j] row = data-row (n), col = weight-col. regs = 4 consec n.
        // out[((b*8+h)*64+d)*1024+n]
        #pragma unroll
        for (int i = 0; i < 4; i++) {
            const int n0 = bm + wm + 16 * i + 4 * fq;     // mult of 4
            const int b = n0 >> 10, nn = n0 & 1023;
            #pragma unroll
            for (int j = 0; j < 4; j++) {
                const int col = bn + wn + 16 * j + fr;
                const float bv2 = bias[col];
                const int h = col >> 6, d = col & 63;
                uint2 pk;
                pk.x = pack2(acc[i][j][0] + bv2, acc[i][j][1] + bv2);
                pk.y = pack2(acc[i][j][2] + bv2, acc[i][j][3] + bv2);
                *(uint2*)(out + ((size_t)(b * 8 + h) * 64 + d) * 1024 + nn) = pk;
            }
        }
    }
}

// ---------------------------------------------------------------------------
// O-projection GEMM (NT), 64x128 tiles, BK=64 single-buffered gll16 staging.
// Operand-swapped (C^T) -> uint2 stores along columns. Grid (128, 4).
// Waves split the 128 weight cols (wave tile: 32 cols x 64 rows).
// ---------------------------------------------------------------------------
__global__ __launch_bounds__(256) void gemm_o(const bf16* __restrict__ A,
                                              const bf16* __restrict__ W,
                                              const float* __restrict__ bias,
                                              bf16* __restrict__ out)
{
    __shared__ bf16 Xs[64 * 64];
    __shared__ bf16 Ws[128 * 64];

    const int tid = threadIdx.x, lane = tid & 63, wave = tid >> 6;
    const int bm = blockIdx.x * 64;
    const int bn = blockIdx.y * 128;

    const int srow = tid >> 3;
    const int sg8  = (((tid & 7) ^ (srow & 7)) * 8);
    const int wn = wave * 32;
    const int fr = lane & 15, fq = lane >> 4;

    f32x4 acc[2][4] = {};
    const bf16* Ap = A + (size_t)(bm + srow) * 512 + sg8;
    const bf16* Wp = W + (size_t)(bn + srow) * 512 + sg8;
    const int ld = 8 * tid;

    for (int k0 = 0; k0 < 512; k0 += 64) {
        __syncthreads();
        #pragma unroll
        for (int c = 0; c < 2; c++)
            gll16(Ap + k0 + (size_t)(32 * c) * 512, Xs + ld + 2048 * c);
        #pragma unroll
        for (int c = 0; c < 4; c++)
            gll16(Wp + k0 + (size_t)(32 * c) * 512, Ws + ld + 2048 * c);
        __syncthreads();

        #pragma unroll
        for (int c2 = 0; c2 < 2; c2++) {
            bf16x8 fx[4], fw[2];
            #pragma unroll
            for (int j = 0; j < 4; j++) {
                const int rx = 16 * j + fr;
                fx[j] = *(const bf16x8*)(&Xs[rx * 64 + (((c2 * 4 + fq) ^ (rx & 7)) * 8)]);
            }
            #pragma unroll
            for (int i = 0; i < 2; i++) {
                const int rw = wn + 16 * i + fr;
                fw[i] = *(const bf16x8*)(&Ws[rw * 64 + (((c2 * 4 + fq) ^ (rw & 7)) * 8)]);
            }
            #pragma unroll
            for (int i = 0; i < 2; i++)
                #pragma unroll
                for (int j = 0; j < 4; j++)
                    acc[i][j] = __builtin_amdgcn_mfma_f32_16x16x32_bf16(fw[i], fx[j], acc[i][j], 0, 0, 0);
        }
    }

    #pragma unroll
    for (int i = 0; i < 2; i++) {
        const int colb = bn + wn + 16 * i + 4 * fq;
        const float4 b4 = *(const float4*)(bias + colb);
        #pragma unroll
        for (int j = 0; j < 4; j++) {
            const int row = bm + 16 * j + fr;
            uint2 pk;
            pk.x = pack2(acc[i][j][0] + b4.x, acc[i][j][1] + b4.y);
            pk.y = pack2(acc[i][j][2] + b4.z, acc[i][j][3] + b4.w);
            *(uint2*)(out + (size_t)row * 512 + colb) = pk;
        }
    }
}

// ---------------------------------------------------------------------------
// MFMA flash attention — S^T form, fixed-max softmax, 32 q-rows per wave
// (2 q-tiles share each K/V fragment read). Round-2 structure:
//   * K AND V staged block-shared via gll16 (reverts round-1's per-wave
//     V-from-global: 4x redundant L2 traffic, unhidden at 2 waves/SIMD).
//   * BOTH buffers double-buffered with counted vmcnt: issue next tile's
//     4 gll16 at iter top, s_waitcnt vmcnt(4) drains only the PREVIOUS
//     tile's staging, raw s_barrier (no vmcnt(0) drain in the main loop).
//   * sched_barrier(0) before end-of-iter barrier keeps PV MFMAs (register
//     -only) from sinking past the barrier into the next staging window.
// LDS 50KB (2x8K Ks + 2x8K Vs + 18K Ps); occupancy grid-bound at 2 blk/CU.
// Qh [b,h,n,64], Kh [b,h,m,64], VhT [b,h,d,m]. Flat grid 512, 4 waves.
// ---------------------------------------------------------------------------
__global__ __launch_bounds__(256) void attn_mfma(const bf16* __restrict__ Qh,
                                                 const bf16* __restrict__ Kh,
                                                 const bf16* __restrict__ VhT,
                                                 bf16* __restrict__ Oc)
{
    __shared__ bf16 Ks[2][64 * 64];
    __shared__ bf16 Vs[2][64 * 64];
    __shared__ bf16 Ps[4][2][16 * 72];

    const int tid = threadIdx.x, lane = tid & 63, w = tid >> 6;
    const int id = blockIdx.x;
    const int bh = (id & 7) * 8 + (id >> 6);       // XCD-local bh grouping
    const int wq = ((id >> 3) & 7) * 128 + w * 32; // wave's first q-row

    const bf16* Qb = Qh  + ((size_t)bh * 1024 + wq) * 64;
    const bf16* Kb = Kh  + (size_t)bh * 1024 * 64;
    const bf16* Vb = VhT + (size_t)bh * 64 * 1024;

    const int fl = lane & 15, fq = lane >> 4;
    const int flk = fl & 7;
    const int gA = (fq ^ flk) * 8;
    const int gB = ((4 | fq) ^ flk) * 8;

    bf16x8 qf[2][2];
    #pragma unroll
    for (int t = 0; t < 2; t++) {
        qf[t][0] = *(const bf16x8*)(Qb + (16 * t + fl) * 64 + fq * 8);
        qf[t][1] = *(const bf16x8*)(Qb + (16 * t + fl) * 64 + 32 + fq * 8);
    }

    f32x4 o[2][4] = {};
    float lsum[2] = {0.f, 0.f};
    const float sc2 = 0.04419417382415922f * 1.4426950408889634f; // /sqrt(512)*log2e

    const int srow = tid >> 3;
    const int sg8  = (((tid & 7) ^ (srow & 7)) * 8);
    const bf16* KbR  = Kb + (size_t)srow * 64 + sg8;
    const bf16* VbR0 = Vb + (size_t)srow * 1024 + sg8;
    const bf16* VbR1 = Vb + (size_t)(srow + 32) * 1024 + sg8;
    const int ld = 8 * tid;

    // prologue: stage tile 0 into buffer 0 (4 gll16 in flight)
    gll16(KbR,           &Ks[0][0] + ld);
    gll16(KbR + 32 * 64, &Ks[0][0] + 2048 + ld);
    gll16(VbR0,          &Vs[0][0] + ld);
    gll16(VbR1,          &Vs[0][0] + 2048 + ld);

    #pragma unroll 1
    for (int kt = 0; kt < 16; kt++) {
        const bf16* Ksc = &Ks[kt & 1][0];
        const bf16* Vsc = &Vs[kt & 1][0];

        // issue NEXT tile's staging into the other buffer, then wait only
        // for the PREVIOUS tile's 4 gll16s (new 4 stay in flight across
        // both barriers — no drain in the main loop).
        if (kt < 15) {
            const int m1 = kt * 64 + 64;
            bf16* Kn = &Ks[(kt + 1) & 1][0];
            bf16* Vn = &Vs[(kt + 1) & 1][0];
            gll16(KbR + (size_t)m1 * 64,        Kn + ld);
            gll16(KbR + (size_t)(m1 + 32) * 64, Kn + 2048 + ld);
            gll16(VbR0 + m1,                    Vn + ld);
            gll16(VbR1 + m1,                    Vn + 2048 + ld);
            asm volatile("s_waitcnt vmcnt(4)" ::: "memory");
        } else {
            asm volatile("s_waitcnt vmcnt(0)" ::: "memory");
        }
        __builtin_amdgcn_s_barrier();   // buf[kt&1] staged block-wide

        // K fragments once, reused by both q-tiles
        bf16x8 kf[4][2];
        #pragma unroll
        for (int tm = 0; tm < 4; tm++) {
            kf[tm][0] = *(const bf16x8*)(&Ksc[(16 * tm + fl) * 64 + gA]);
            kf[tm][1] = *(const bf16x8*)(&Ksc[(16 * tm + fl) * 64 + gB]);
        }

        #pragma unroll
        for (int t = 0; t < 2; t++) {
            f32x4 st[4] = {};
            #pragma unroll
            for (int tm = 0; tm < 4; tm++) {
                st[tm] = __builtin_amdgcn_mfma_f32_16x16x32_bf16(kf[tm][0], qf[t][0], st[tm], 0, 0, 0);
                st[tm] = __builtin_amdgcn_mfma_f32_16x16x32_bf16(kf[tm][1], qf[t][1], st[tm], 0, 0, 0);
            }
            #pragma unroll
            for (int tm = 0; tm < 4; tm++) {
                float p0 = __builtin_amdgcn_exp2f(st[tm][0] * sc2);
                float p1 = __builtin_amdgcn_exp2f(st[tm][1] * sc2);
                float p2 = __builtin_amdgcn_exp2f(st[tm][2] * sc2);
                float p3 = __builtin_amdgcn_exp2f(st[tm][3] * sc2);
                lsum[t] += (p0 + p1) + (p2 + p3);
                uint2 pk;
                pk.x = pack2(p0, p1);
                pk.y = pack2(p2, p3);
                *(uint2*)(&Ps[w][t][fl * 72 + 16 * tm + fq * 4]) = pk;
            }
        }

        // V^T fragments once, reused by both q-tiles
        bf16x8 vf[4][2];
        #pragma unroll
        for (int jd = 0; jd < 4; jd++) {
            vf[jd][0] = *(const bf16x8*)(&Vsc[(16 * jd + fl) * 64 + gA]);
            vf[jd][1] = *(const bf16x8*)(&Vsc[(16 * jd + fl) * 64 + gB]);
        }
        #pragma unroll
        for (int t = 0; t < 2; t++) {
            bf16x8 pf0 = *(const bf16x8*)(&Ps[w][t][fl * 72 + fq * 8]);
            bf16x8 pf1 = *(const bf16x8*)(&Ps[w][t][fl * 72 + 32 + fq * 8]);
            #pragma unroll
            for (int jd = 0; jd < 4; jd++) {
                o[t][jd] = __builtin_amdgcn_mfma_f32_16x16x32_bf16(vf[jd][0], pf0, o[t][jd], 0, 0, 0);
                o[t][jd] = __builtin_amdgcn_mfma_f32_16x16x32_bf16(vf[jd][1], pf1, o[t][jd], 0, 0, 0);
            }
        }

        __builtin_amdgcn_sched_barrier(0);
        __builtin_amdgcn_s_barrier();   // all waves done reading buf[kt&1]
    }

    const int b = bh >> 3, h = bh & 7;
    #pragma unroll
    for (int t = 0; t < 2; t++) {
        float ls = lsum[t];
        ls += __shfl_xor(ls, 16);
        ls += __shfl_xor(ls, 32);
        const float linv = 1.f / ls;
        const size_t obase = ((size_t)(b * 1024 + wq + 16 * t + fl)) * 512 + h * 64;
        #pragma unroll
        for (int jd = 0; jd < 4; jd++) {
            const ushort4 qr = *(const ushort4*)(Qb + (16 * t + fl) * 64 + 16 * jd + fq * 4);
            uint2 w2;
            w2.x = pack2(o[t][jd][0] * linv + bfu2f(qr.x), o[t][jd][1] * linv + bfu2f(qr.y));
            w2.y = pack2(o[t][jd][2] * linv + bfu2f(qr.z), o[t][jd][3] * linv + bfu2f(qr.w));
            *(uint2*)(&Oc[obase + 16 * jd + fq * 4]) = w2;
        }
    }
}

// ---------------------------------------------------------------------------
// LayerNorm over rows of 512 — wave/row, 8 consecutive elems/lane.
// ---------------------------------------------------------------------------
__global__ __launch_bounds__(256) void ln0(const bf16* __restrict__ X,
                                           const float* __restrict__ g,
                                           const float* __restrict__ be,
                                           bf16* __restrict__ Y)
{
    const int lane = threadIdx.x & 63;
    const int row = blockIdx.x * 4 + (threadIdx.x >> 6);
    const size_t base = (size_t)row * 512 + lane * 8;
    const bf16x8 xv = *(const bf16x8*)(X + base);
    float x[8];
    #pragma unroll
    for (int j = 0; j < 8; j++) x[j] = bfu2f((unsigned short)xv[j]);
    float s = 0.f, s2 = 0.f;
    #pragma unroll
    for (int j = 0; j < 8; j++) { s += x[j]; s2 += x[j] * x[j]; }
    s = wave_sum(s); s2 = wave_sum(s2);
    const float mean = s * (1.f / 512.f);
    const float var = s2 * (1.f / 512.f) - mean * mean;
    const float rs = rsqrtf(fmaxf(var, 0.f) + 1e-5f);
    const float4 gv0 = *(const float4*)(g + lane * 8);
    const float4 gv1 = *(const float4*)(g + lane * 8 + 4);
    const float4 bv0 = *(const float4*)(be + lane * 8);
    const float4 bv1 = *(const float4*)(be + lane * 8 + 4);
    uint4 ov;
    ov.x = pack2((x[0]-mean)*rs*gv0.x + bv0.x, (x[1]-mean)*rs*gv0.y + bv0.y);
    ov.y = pack2((x[2]-mean)*rs*gv0.z + bv0.z, (x[3]-mean)*rs*gv0.w + bv0.w);
    ov.z = pack2((x[4]-mean)*rs*gv1.x + bv1.x, (x[5]-mean)*rs*gv1.y + bv1.y);
    ov.w = pack2((x[6]-mean)*rs*gv1.z + bv1.z, (x[7]-mean)*rs*gv1.w + bv1.w);
    *(uint4*)(Y + base) = ov;
}

__global__ __launch_bounds__(256) void ln1(const bf16* __restrict__ X,
                                           const bf16* __restrict__ R,
                                           const float* __restrict__ g,
                                           const float* __restrict__ be,
                                           float* __restrict__ Y)
{
    const int lane = threadIdx.x & 63;
    const int row = blockIdx.x * 4 + (threadIdx.x >> 6);
    const size_t base = (size_t)row * 512 + lane * 8;
    const bf16x8 xv = *(const bf16x8*)(X + base);
    const bf16x8 rv = *(const bf16x8*)(R + base);
    float x[8];
    #pragma unroll
    for (int j = 0; j < 8; j++)
        x[j] = bfu2f((unsigned short)rv[j]) + fmaxf(bfu2f((unsigned short)xv[j]), 0.f);
    float s = 0.f, s2 = 0.f;
    #pragma unroll
    for (int j = 0; j < 8; j++) { s += x[j]; s2 += x[j] * x[j]; }
    s = wave_sum(s); s2 = wave_sum(s2);
    const float mean = s * (1.f / 512.f);
    const float var = s2 * (1.f / 512.f) - mean * mean;
    const float rs = rsqrtf(fmaxf(var, 0.f) + 1e-5f);
    const float4 gv0 = *(const float4*)(g + lane * 8);
    const float4 gv1 = *(const float4*)(g + lane * 8 + 4);
    const float4 bv0 = *(const float4*)(be + lane * 8);
    const float4 bv1 = *(const float4*)(be + lane * 8 + 4);
    float4 y0, y1;
    y0.x = (x[0]-mean)*rs*gv0.x + bv0.x; y0.y = (x[1]-mean)*rs*gv0.y + bv0.y;
    y0.z = (x[2]-mean)*rs*gv0.z + bv0.z; y0.w = (x[3]-mean)*rs*gv0.w + bv0.w;
    y1.x = (x[4]-mean)*rs*gv1.x + bv1.x; y1.y = (x[5]-mean)*rs*gv1.y + bv1.y;
    y1.z = (x[6]-mean)*rs*gv1.z + bv1.z; y1.w = (x[7]-mean)*rs*gv1.w + bv1.w;
    *(float4*)(Y + base)     = y0;
    *(float4*)(Y + base + 4) = y1;
}

// ---------------------------------------------------------------------------
extern "C" void kernel_launch(void* const* d_in, const int* in_sizes, int n_in,
                              void* d_out, int out_size, void* d_ws, size_t ws_size,
                              hipStream_t stream)
{
    const float* Q   = (const float*)d_in[0];
    const float* K   = (const float*)d_in[1];
    const float* Wq  = (const float*)d_in[2];
    const float* bq  = (const float*)d_in[3];
    const float* Wk  = (const float*)d_in[4];
    const float* bk  = (const float*)d_in[5];
    const float* Wv  = (const float*)d_in[6];
    const float* bv  = (const float*)d_in[7];
    const float* Wo  = (const float*)d_in[8];
    const float* bo  = (const float*)d_in[9];
    const float* g0  = (const float*)d_in[10];
    const float* be0 = (const float*)d_in[11];
    const float* g1  = (const float*)d_in[12];
    const float* be1 = (const float*)d_in[13];
    float* out = (float*)d_out;

    const size_t NQK = (size_t)8 * 1024 * 512;  // 4M
    const size_t NW  = (size_t)512 * 512;       // 256K
    bf16* ws   = (bf16*)d_ws;
    bf16* cQ   = ws;
    bf16* cK   = cQ + NQK;
    bf16* cWq  = cK + NQK;
    bf16* cWk  = cWq + NW;
    bf16* cWv  = cWk + NW;
    bf16* cWo  = cWv + NW;
    bf16* pQh  = cWo + NW;           // [b,h,n,d]
    bf16* pKh  = pQh + NQK;          // [b,h,m,d]
    bf16* pVhT = pKh + NQK;          // [b,h,d,m]
    bf16* pOc  = (bf16*)d_out;       // attn output staged in d_out
    bf16* pO1  = pKh;                // Kh dead after attn
    bf16* pTmp = pQh;                // Qh dead after attn

    castall<<<2304, 256, 0, stream>>>(Q, K, Wq, Wk, Wv, Wo, cQ, cK, cWq, cWk, cWv, cWo);
    gemm_qkv<<<dim3(64, 12), 256, 0, stream>>>(cQ, cK, cWq, cWk, cWv, bq, bk, bv, pQh, pKh, pVhT);
    attn_mfma<<<512, 256, 0, stream>>>(pQh, pKh, pVhT, pOc);
    ln0<<<2048, 256, 0, stream>>>(pOc, g0, be0, pO1);
    gemm_o<<<dim3(128, 4), 256, 0, stream>>>(pO1, cWo, bo, pTmp);
    ln1<<<2048, 256, 0, stream>>>(pTmp, pO1, g1, be1, out);
}

// Round 3
// 187.461 us; speedup vs baseline: 1.0416x; 1.0009x over previous
//
#include <hip/hip_runtime.h>
#include <hip/hip_bf16.h>

typedef __hip_bfloat16 bf16;
typedef short bf16x8 __attribute__((ext_vector_type(8)));
typedef float f32x4 __attribute__((ext_vector_type(4)));
typedef unsigned int u32;

static __device__ __forceinline__ float bfu2f(unsigned short u) { return __uint_as_float((u32)u << 16); }
static __device__ __forceinline__ u32 pack2(float a, float b) {
    return (u32)__bfloat16_as_ushort(__float2bfloat16(a))
         | ((u32)__bfloat16_as_ushort(__float2bfloat16(b)) << 16);
}
static __device__ __forceinline__ float wave_sum(float v) {
    #pragma unroll
    for (int off = 32; off > 0; off >>= 1) v += __shfl_xor(v, off);
    return v;
}

// async global->LDS 16B copy (wave-uniform LDS base + lane*16 by HW).
static __device__ __forceinline__ void gll16(const bf16* g, bf16* l) {
    __builtin_amdgcn_global_load_lds((const __attribute__((address_space(1))) void*)g,
                                     (__attribute__((address_space(3))) void*)l,
                                     16, 0, 0);
}

// ---------------------------------------------------------------------------
// Fused fp32->bf16 cast of Q, K, Wq, Wk, Wv, Wo. 4096 elems/block, 16/thread.
// ---------------------------------------------------------------------------
__global__ __launch_bounds__(256) void castall(const float* __restrict__ Q,  const float* __restrict__ K,
                                               const float* __restrict__ Wq, const float* __restrict__ Wk,
                                               const float* __restrict__ Wv, const float* __restrict__ Wo,
                                               bf16* __restrict__ dQ,  bf16* __restrict__ dK,
                                               bf16* __restrict__ dWq, bf16* __restrict__ dWk,
                                               bf16* __restrict__ dWv, bf16* __restrict__ dWo)
{
    const int b = blockIdx.x;
    const float* src; bf16* dst; size_t off;
    if (b < 1024)      { src = Q;  dst = dQ;  off = (size_t)b * 4096; }
    else if (b < 2048) { src = K;  dst = dK;  off = (size_t)(b - 1024) * 4096; }
    else {
        const int wb = b - 2048, wi = wb >> 6;
        off = (size_t)(wb & 63) * 4096;
        src = wi == 0 ? Wq : wi == 1 ? Wk : wi == 2 ? Wv : Wo;
        dst = wi == 0 ? dWq : wi == 1 ? dWk : wi == 2 ? dWv : dWo;
    }
    const size_t p = off + threadIdx.x * 16;
    const float4 v0 = *(const float4*)(src + p);
    const float4 v1 = *(const float4*)(src + p + 4);
    const float4 v2 = *(const float4*)(src + p + 8);
    const float4 v3 = *(const float4*)(src + p + 12);
    uint4 o0, o1;
    o0.x = pack2(v0.x, v0.y); o0.y = pack2(v0.z, v0.w);
    o0.z = pack2(v1.x, v1.y); o0.w = pack2(v1.z, v1.w);
    o1.x = pack2(v2.x, v2.y); o1.y = pack2(v2.z, v2.w);
    o1.z = pack2(v3.x, v3.y); o1.w = pack2(v3.z, v3.w);
    *(uint4*)(dst + p)     = o0;
    *(uint4*)(dst + p + 8) = o1;
}

// ---------------------------------------------------------------------------
// Fused QKV projection GEMM (NT), 128x128 tiles, BK=64 single-buffered
// gll16 staging (8 iters, 2 barriers each), unpadded [128][64] LDS with
// granule swizzle LDS[row][g] = glob[row][g ^ (row&7)].
// Q/K-proj compute C^T (operand-swapped) so a lane's 4 acc regs are 4
// consecutive d -> uint2 stores; V-proj computes C normally (regs = 4
// consecutive n, contiguous in the [b,h,d,n] layout). Grid (64, 12).
// ---------------------------------------------------------------------------
__global__ __launch_bounds__(256) void gemm_qkv(const bf16* __restrict__ Aq, const bf16* __restrict__ Ak,
                                                const bf16* __restrict__ Wq, const bf16* __restrict__ Wk,
                                                const bf16* __restrict__ Wv,
                                                const float* __restrict__ bq, const float* __restrict__ bk,
                                                const float* __restrict__ bv,
                                                bf16* __restrict__ oQ, bf16* __restrict__ oK,
                                                bf16* __restrict__ oV)
{
    __shared__ bf16 Xs[128 * 64];
    __shared__ bf16 Ws[128 * 64];

    const int tid = threadIdx.x, lane = tid & 63, wave = tid >> 6;
    const int yy = blockIdx.y, wi = yy >> 2;
    const bf16* A     = wi == 0 ? Aq : Ak;
    const bf16* W     = wi == 0 ? Wq : wi == 1 ? Wk : Wv;
    const float* bias = wi == 0 ? bq : wi == 1 ? bk : bv;
    bf16* out         = wi == 0 ? oQ : wi == 1 ? oK : oV;
    const bool vmode  = (wi == 2);
    const int bm = blockIdx.x * 128;
    const int bn = (yy & 3) * 128;

    // staging: slot s = tid + 256c -> row (tid>>3)+32c, lds granule tid&7,
    // source granule (tid&7)^((tid>>3)&7)
    const int srow = tid >> 3;
    const int sg8  = (((tid & 7) ^ (srow & 7)) * 8);
    const int wm = (wave >> 1) * 64, wn = (wave & 1) * 64;
    const int fr = lane & 15, fq = lane >> 4;

    f32x4 acc[4][4] = {};
    const bf16* Ap = A + (size_t)(bm + srow) * 512 + sg8;
    const bf16* Wp = W + (size_t)(bn + srow) * 512 + sg8;
    const int ld = 8 * tid;

    for (int k0 = 0; k0 < 512; k0 += 64) {
        __syncthreads();
        #pragma unroll
        for (int c = 0; c < 4; c++) {
            gll16(Ap + k0 + (size_t)(32 * c) * 512, Xs + ld + 2048 * c);
            gll16(Wp + k0 + (size_t)(32 * c) * 512, Ws + ld + 2048 * c);
        }
        __syncthreads();

        #pragma unroll
        for (int c2 = 0; c2 < 2; c2++) {
            bf16x8 fx[4], fw[4];
            #pragma unroll
            for (int i = 0; i < 4; i++) {
                const int rx = wm + 16 * i + fr;
                const int rw = wn + 16 * i + fr;
                fx[i] = *(const bf16x8*)(&Xs[rx * 64 + (((c2 * 4 + fq) ^ (rx & 7)) * 8)]);
                fw[i] = *(const bf16x8*)(&Ws[rw * 64 + (((c2 * 4 + fq) ^ (rw & 7)) * 8)]);
            }
            if (vmode) {
                #pragma unroll
                for (int i = 0; i < 4; i++)
                    #pragma unroll
                    for (int j = 0; j < 4; j++)
                        acc[i][j] = __builtin_amdgcn_mfma_f32_16x16x32_bf16(fx[i], fw[j], acc[i][j], 0, 0, 0);
            } else {
                #pragma unroll
                for (int i = 0; i < 4; i++)
                    #pragma unroll
                    for (int j = 0; j < 4; j++)
                        acc[i][j] = __builtin_amdgcn_mfma_f32_16x16x32_bf16(fw[i], fx[j], acc[i][j], 0, 0, 0);
            }
        }
    }

    if (!vmode) {
        // C^T: acc[i][j] row = weight-col (d_full), col = data-row (n).
        // lane regs r -> 4 consecutive d. out[((b*8+h)*1024+n)*64+d]
        #pragma unroll
        for (int i = 0; i < 4; i++) {
            const int colb = bn + wn + 16 * i + 4 * fq;   // d_full base (mult of 4)
            const float4 b4 = *(const float4*)(bias + colb);
            const int h = colb >> 6, d0 = colb & 63;
            #pragma unroll
            for (int j = 0; j < 4; j++) {
                const int n = bm + wm + 16 * j + fr;
                const int b = n >> 10, nn = n & 1023;
                uint2 pk;
                pk.x = pack2(acc[i][j][0] + b4.x, acc[i][j][1] + b4.y);
                pk.y = pack2(acc[i][j][2] + b4.z, acc[i][j][3] + b4.w);
                *(uint2*)(out + ((size_t)(b * 8 + h) * 1024 + nn) * 64 + d0) = pk;
            }
        }
    } else {
        // C: acc[i][j] row = data-row (n), col = weight-col. regs = 4 consec n.
        // out[((b*8+h)*64+d)*1024+n]
        #pragma unroll
        for (int i = 0; i < 4; i++) {
            const int n0 = bm + wm + 16 * i + 4 * fq;     // mult of 4
            const int b = n0 >> 10, nn = n0 & 1023;
            #pragma unroll
            for (int j = 0; j < 4; j++) {
                const int col = bn + wn + 16 * j + fr;
                const float bv2 = bias[col];
                const int h = col >> 6, d = col & 63;
                uint2 pk;
                pk.x = pack2(acc[i][j][0] + bv2, acc[i][j][1] + bv2);
                pk.y = pack2(acc[i][j][2] + bv2, acc[i][j][3] + bv2);
                *(uint2*)(out + ((size_t)(b * 8 + h) * 64 + d) * 1024 + nn) = pk;
            }
        }
    }
}

// ---------------------------------------------------------------------------
// O-projection GEMM (NT), 64x128 tiles, BK=64 single-buffered gll16 staging.
// Operand-swapped (C^T) -> uint2 stores along columns. Grid (128, 4).
// Waves split the 128 weight cols (wave tile: 32 cols x 64 rows).
// ---------------------------------------------------------------------------
__global__ __launch_bounds__(256) void gemm_o(const bf16* __restrict__ A,
                                              const bf16* __restrict__ W,
                                              const float* __restrict__ bias,
                                              bf16* __restrict__ out)
{
    __shared__ bf16 Xs[64 * 64];
    __shared__ bf16 Ws[128 * 64];

    const int tid = threadIdx.x, lane = tid & 63, wave = tid >> 6;
    const int bm = blockIdx.x * 64;
    const int bn = blockIdx.y * 128;

    const int srow = tid >> 3;
    const int sg8  = (((tid & 7) ^ (srow & 7)) * 8);
    const int wn = wave * 32;
    const int fr = lane & 15, fq = lane >> 4;

    f32x4 acc[2][4] = {};
    const bf16* Ap = A + (size_t)(bm + srow) * 512 + sg8;
    const bf16* Wp = W + (size_t)(bn + srow) * 512 + sg8;
    const int ld = 8 * tid;

    for (int k0 = 0; k0 < 512; k0 += 64) {
        __syncthreads();
        #pragma unroll
        for (int c = 0; c < 2; c++)
            gll16(Ap + k0 + (size_t)(32 * c) * 512, Xs + ld + 2048 * c);
        #pragma unroll
        for (int c = 0; c < 4; c++)
            gll16(Wp + k0 + (size_t)(32 * c) * 512, Ws + ld + 2048 * c);
        __syncthreads();

        #pragma unroll
        for (int c2 = 0; c2 < 2; c2++) {
            bf16x8 fx[4], fw[2];
            #pragma unroll
            for (int j = 0; j < 4; j++) {
                const int rx = 16 * j + fr;
                fx[j] = *(const bf16x8*)(&Xs[rx * 64 + (((c2 * 4 + fq) ^ (rx & 7)) * 8)]);
            }
            #pragma unroll
            for (int i = 0; i < 2; i++) {
                const int rw = wn + 16 * i + fr;
                fw[i] = *(const bf16x8*)(&Ws[rw * 64 + (((c2 * 4 + fq) ^ (rw & 7)) * 8)]);
            }
            #pragma unroll
            for (int i = 0; i < 2; i++)
                #pragma unroll
                for (int j = 0; j < 4; j++)
                    acc[i][j] = __builtin_amdgcn_mfma_f32_16x16x32_bf16(fw[i], fx[j], acc[i][j], 0, 0, 0);
        }
    }

    #pragma unroll
    for (int i = 0; i < 2; i++) {
        const int colb = bn + wn + 16 * i + 4 * fq;
        const float4 b4 = *(const float4*)(bias + colb);
        #pragma unroll
        for (int j = 0; j < 4; j++) {
            const int row = bm + 16 * j + fr;
            uint2 pk;
            pk.x = pack2(acc[i][j][0] + b4.x, acc[i][j][1] + b4.y);
            pk.y = pack2(acc[i][j][2] + b4.z, acc[i][j][3] + b4.w);
            *(uint2*)(out + (size_t)row * 512 + colb) = pk;
        }
    }
}

// ---------------------------------------------------------------------------
// MFMA flash attention — S^T form, fixed-max softmax. Round-3 structure:
// OCCUPANCY DOUBLED: 16 q-rows per wave (one q-tile), grid 1024
// (64 bh x 16 q-blocks), 4 waves/block. LDS 25KB (8K Ks + 8K Vs + 9K Ps)
// -> 4 blocks/CU = 16 waves/CU = 4 waves/SIMD (was 2). Single-buffered
// round-0 staging loop (dbuf measured neutral at r2); the per-iter drain
// is hidden by 3 other resident blocks at different loop phases.
// Qh [b,h,n,64], Kh [b,h,m,64], VhT [b,h,d,m]. XCD-local bh grouping.
// ---------------------------------------------------------------------------
__global__ __launch_bounds__(256) void attn_mfma(const bf16* __restrict__ Qh,
                                                 const bf16* __restrict__ Kh,
                                                 const bf16* __restrict__ VhT,
                                                 bf16* __restrict__ Oc)
{
    __shared__ bf16 Ks[64 * 64];
    __shared__ bf16 Vs[64 * 64];
    __shared__ bf16 Ps[4][16 * 72];

    const int tid = threadIdx.x, lane = tid & 63, w = tid >> 6;
    const int id = blockIdx.x;
    const int bh = (id & 7) * 8 + (id >> 7);        // XCD-local bh grouping
    const int wq = ((id >> 3) & 15) * 64 + w * 16;  // wave's q-tile (16 rows)

    const bf16* Qb = Qh  + ((size_t)bh * 1024 + wq) * 64;
    const bf16* Kb = Kh  + (size_t)bh * 1024 * 64;
    const bf16* Vb = VhT + (size_t)bh * 64 * 1024;

    const int fl = lane & 15, fq = lane >> 4;
    const int flk = fl & 7;
    const int gA = (fq ^ flk) * 8;
    const int gB = ((4 | fq) ^ flk) * 8;

    bf16x8 qf[2];
    qf[0] = *(const bf16x8*)(Qb + fl * 64 + fq * 8);
    qf[1] = *(const bf16x8*)(Qb + fl * 64 + 32 + fq * 8);

    f32x4 o[4] = {};
    float lsum = 0.f;
    const float sc2 = 0.04419417382415922f * 1.4426950408889634f; // /sqrt(512)*log2e

    const int srow = tid >> 3;
    const int sg8  = (((tid & 7) ^ (srow & 7)) * 8);
    const bf16* KbR  = Kb + (size_t)srow * 64 + sg8;
    const bf16* VbR0 = Vb + (size_t)srow * 1024 + sg8;
    const bf16* VbR1 = Vb + (size_t)(srow + 32) * 1024 + sg8;
    const int ld = 8 * tid;

    for (int kt = 0; kt < 16; kt++) {
        const int m0 = kt * 64;
        __syncthreads();
        gll16(KbR + (size_t)m0 * 64,        Ks + ld);
        gll16(KbR + (size_t)(m0 + 32) * 64, Ks + 2048 + ld);
        gll16(VbR0 + m0,                    Vs + ld);
        gll16(VbR1 + m0,                    Vs + 2048 + ld);
        __syncthreads();

        // K fragments (full 64x64 K tile per wave)
        bf16x8 kf[4][2];
        #pragma unroll
        for (int tm = 0; tm < 4; tm++) {
            kf[tm][0] = *(const bf16x8*)(&Ks[(16 * tm + fl) * 64 + gA]);
            kf[tm][1] = *(const bf16x8*)(&Ks[(16 * tm + fl) * 64 + gB]);
        }

        f32x4 st[4] = {};
        #pragma unroll
        for (int tm = 0; tm < 4; tm++) {
            st[tm] = __builtin_amdgcn_mfma_f32_16x16x32_bf16(kf[tm][0], qf[0], st[tm], 0, 0, 0);
            st[tm] = __builtin_amdgcn_mfma_f32_16x16x32_bf16(kf[tm][1], qf[1], st[tm], 0, 0, 0);
        }
        #pragma unroll
        for (int tm = 0; tm < 4; tm++) {
            float p0 = __builtin_amdgcn_exp2f(st[tm][0] * sc2);
            float p1 = __builtin_amdgcn_exp2f(st[tm][1] * sc2);
            float p2 = __builtin_amdgcn_exp2f(st[tm][2] * sc2);
            float p3 = __builtin_amdgcn_exp2f(st[tm][3] * sc2);
            lsum += (p0 + p1) + (p2 + p3);
            uint2 pk;
            pk.x = pack2(p0, p1);
            pk.y = pack2(p2, p3);
            *(uint2*)(&Ps[w][fl * 72 + 16 * tm + fq * 4]) = pk;
        }

        // V^T fragments
        bf16x8 vf[4][2];
        #pragma unroll
        for (int jd = 0; jd < 4; jd++) {
            vf[jd][0] = *(const bf16x8*)(&Vs[(16 * jd + fl) * 64 + gA]);
            vf[jd][1] = *(const bf16x8*)(&Vs[(16 * jd + fl) * 64 + gB]);
        }
        bf16x8 pf0 = *(const bf16x8*)(&Ps[w][fl * 72 + fq * 8]);
        bf16x8 pf1 = *(const bf16x8*)(&Ps[w][fl * 72 + 32 + fq * 8]);
        #pragma unroll
        for (int jd = 0; jd < 4; jd++) {
            o[jd] = __builtin_amdgcn_mfma_f32_16x16x32_bf16(vf[jd][0], pf0, o[jd], 0, 0, 0);
            o[jd] = __builtin_amdgcn_mfma_f32_16x16x32_bf16(vf[jd][1], pf1, o[jd], 0, 0, 0);
        }
    }

    const int b = bh >> 3, h = bh & 7;
    float ls = lsum;
    ls += __shfl_xor(ls, 16);
    ls += __shfl_xor(ls, 32);
    const float linv = 1.f / ls;
    const size_t obase = ((size_t)(b * 1024 + wq + fl)) * 512 + h * 64;
    #pragma unroll
    for (int jd = 0; jd < 4; jd++) {
        const ushort4 qr = *(const ushort4*)(Qb + fl * 64 + 16 * jd + fq * 4);
        uint2 w2;
        w2.x = pack2(o[jd][0] * linv + bfu2f(qr.x), o[jd][1] * linv + bfu2f(qr.y));
        w2.y = pack2(o[jd][2] * linv + bfu2f(qr.z), o[jd][3] * linv + bfu2f(qr.w));
        *(uint2*)(&Oc[obase + 16 * jd + fq * 4]) = w2;
    }
}

// ---------------------------------------------------------------------------
// LayerNorm over rows of 512 — wave/row, 8 consecutive elems/lane.
// ---------------------------------------------------------------------------
__global__ __launch_bounds__(256) void ln0(const bf16* __restrict__ X,
                                           const float* __restrict__ g,
                                           const float* __restrict__ be,
                                           bf16* __restrict__ Y)
{
    const int lane = threadIdx.x & 63;
    const int row = blockIdx.x * 4 + (threadIdx.x >> 6);
    const size_t base = (size_t)row * 512 + lane * 8;
    const bf16x8 xv = *(const bf16x8*)(X + base);
    float x[8];
    #pragma unroll
    for (int j = 0; j < 8; j++) x[j] = bfu2f((unsigned short)xv[j]);
    float s = 0.f, s2 = 0.f;
    #pragma unroll
    for (int j = 0; j < 8; j++) { s += x[j]; s2 += x[j] * x[j]; }
    s = wave_sum(s); s2 = wave_sum(s2);
    const float mean = s * (1.f / 512.f);
    const float var = s2 * (1.f / 512.f) - mean * mean;
    const float rs = rsqrtf(fmaxf(var, 0.f) + 1e-5f);
    const float4 gv0 = *(const float4*)(g + lane * 8);
    const float4 gv1 = *(const float4*)(g + lane * 8 + 4);
    const float4 bv0 = *(const float4*)(be + lane * 8);
    const float4 bv1 = *(const float4*)(be + lane * 8 + 4);
    uint4 ov;
    ov.x = pack2((x[0]-mean)*rs*gv0.x + bv0.x, (x[1]-mean)*rs*gv0.y + bv0.y);
    ov.y = pack2((x[2]-mean)*rs*gv0.z + bv0.z, (x[3]-mean)*rs*gv0.w + bv0.w);
    ov.z = pack2((x[4]-mean)*rs*gv1.x + bv1.x, (x[5]-mean)*rs*gv1.y + bv1.y);
    ov.w = pack2((x[6]-mean)*rs*gv1.z + bv1.z, (x[7]-mean)*rs*gv1.w + bv1.w);
    *(uint4*)(Y + base) = ov;
}

__global__ __launch_bounds__(256) void ln1(const bf16* __restrict__ X,
                                           const bf16* __restrict__ R,
                                           const float* __restrict__ g,
                                           const float* __restrict__ be,
                                           float* __restrict__ Y)
{
    const int lane = threadIdx.x & 63;
    const int row = blockIdx.x * 4 + (threadIdx.x >> 6);
    const size_t base = (size_t)row * 512 + lane * 8;
    const bf16x8 xv = *(const bf16x8*)(X + base);
    const bf16x8 rv = *(const bf16x8*)(R + base);
    float x[8];
    #pragma unroll
    for (int j = 0; j < 8; j++)
        x[j] = bfu2f((unsigned short)rv[j]) + fmaxf(bfu2f((unsigned short)xv[j]), 0.f);
    float s = 0.f, s2 = 0.f;
    #pragma unroll
    for (int j = 0; j < 8; j++) { s += x[j]; s2 += x[j] * x[j]; }
    s = wave_sum(s); s2 = wave_sum(s2);
    const float mean = s * (1.f / 512.f);
    const float var = s2 * (1.f / 512.f) - mean * mean;
    const float rs = rsqrtf(fmaxf(var, 0.f) + 1e-5f);
    const float4 gv0 = *(const float4*)(g + lane * 8);
    const float4 gv1 = *(const float4*)(g + lane * 8 + 4);
    const float4 bv0 = *(const float4*)(be + lane * 8);
    const float4 bv1 = *(const float4*)(be + lane * 8 + 4);
    float4 y0, y1;
    y0.x = (x[0]-mean)*rs*gv0.x + bv0.x; y0.y = (x[1]-mean)*rs*gv0.y + bv0.y;
    y0.z = (x[2]-mean)*rs*gv0.z + bv0.z; y0.w = (x[3]-mean)*rs*gv0.w + bv0.w;
    y1.x = (x[4]-mean)*rs*gv1.x + bv1.x; y1.y = (x[5]-mean)*rs*gv1.y + bv1.y;
    y1.z = (x[6]-mean)*rs*gv1.z + bv1.z; y1.w = (x[7]-mean)*rs*gv1.w + bv1.w;
    *(float4*)(Y + base)     = y0;
    *(float4*)(Y + base + 4) = y1;
}

// ---------------------------------------------------------------------------
extern "C" void kernel_launch(void* const* d_in, const int* in_sizes, int n_in,
                              void* d_out, int out_size, void* d_ws, size_t ws_size,
                              hipStream_t stream)
{
    const float* Q   = (const float*)d_in[0];
    const float* K   = (const float*)d_in[1];
    const float* Wq  = (const float*)d_in[2];
    const float* bq  = (const float*)d_in[3];
    const float* Wk  = (const float*)d_in[4];
    const float* bk  = (const float*)d_in[5];
    const float* Wv  = (const float*)d_in[6];
    const float* bv  = (const float*)d_in[7];
    const float* Wo  = (const float*)d_in[8];
    const float* bo  = (const float*)d_in[9];
    const float* g0  = (const float*)d_in[10];
    const float* be0 = (const float*)d_in[11];
    const float* g1  = (const float*)d_in[12];
    const float* be1 = (const float*)d_in[13];
    float* out = (float*)d_out;

    const size_t NQK = (size_t)8 * 1024 * 512;  // 4M
    const size_t NW  = (size_t)512 * 512;       // 256K
    bf16* ws   = (bf16*)d_ws;
    bf16* cQ   = ws;
    bf16* cK   = cQ + NQK;
    bf16* cWq  = cK + NQK;
    bf16* cWk  = cWq + NW;
    bf16* cWv  = cWk + NW;
    bf16* cWo  = cWv + NW;
    bf16* pQh  = cWo + NW;           // [b,h,n,d]
    bf16* pKh  = pQh + NQK;          // [b,h,m,d]
    bf16* pVhT = pKh + NQK;          // [b,h,d,m]
    bf16* pOc  = (bf16*)d_out;       // attn output staged in d_out
    bf16* pO1  = pKh;                // Kh dead after attn
    bf16* pTmp = pQh;                // Qh dead after attn

    castall<<<2304, 256, 0, stream>>>(Q, K, Wq, Wk, Wv, Wo, cQ, cK, cWq, cWk, cWv, cWo);
    gemm_qkv<<<dim3(64, 12), 256, 0, stream>>>(cQ, cK, cWq, cWk, cWv, bq, bk, bv, pQh, pKh, pVhT);
    attn_mfma<<<1024, 256, 0, stream>>>(pQh, pKh, pVhT, pOc);
    ln0<<<2048, 256, 0, stream>>>(pOc, g0, be0, pO1);
    gemm_o<<<dim3(128, 4), 256, 0, stream>>>(pO1, cWo, bo, pTmp);
    ln1<<<2048, 256, 0, stream>>>(pTmp, pO1, g1, be1, out);
}

// Round 5
// 186.252 us; speedup vs baseline: 1.0484x; 1.0065x over previous
//
#include <hip/hip_runtime.h>
#include <hip/hip_bf16.h>

typedef __hip_bfloat16 bf16;
typedef short bf16x8 __attribute__((ext_vector_type(8)));
typedef float f32x4 __attribute__((ext_vector_type(4)));
typedef unsigned int u32;

static __device__ __forceinline__ float bfu2f(unsigned short u) { return __uint_as_float((u32)u << 16); }
static __device__ __forceinline__ u32 pack2(float a, float b) {
    return (u32)__bfloat16_as_ushort(__float2bfloat16(a))
         | ((u32)__bfloat16_as_ushort(__float2bfloat16(b)) << 16);
}
static __device__ __forceinline__ float wave_sum(float v) {
    #pragma unroll
    for (int off = 32; off > 0; off >>= 1) v += __shfl_xor(v, off);
    return v;
}

// async global->LDS 16B copy (wave-uniform LDS base + lane*16 by HW).
static __device__ __forceinline__ void gll16(const bf16* g, bf16* l) {
    __builtin_amdgcn_global_load_lds((const __attribute__((address_space(1))) void*)g,
                                     (__attribute__((address_space(3))) void*)l,
                                     16, 0, 0);
}

// ---------------------------------------------------------------------------
// Fused fp32->bf16 cast of Q, K, Wq, Wk, Wv, Wo. 4096 elems/block, 16/thread.
// ---------------------------------------------------------------------------
__global__ __launch_bounds__(256) void castall(const float* __restrict__ Q,  const float* __restrict__ K,
                                               const float* __restrict__ Wq, const float* __restrict__ Wk,
                                               const float* __restrict__ Wv, const float* __restrict__ Wo,
                                               bf16* __restrict__ dQ,  bf16* __restrict__ dK,
                                               bf16* __restrict__ dWq, bf16* __restrict__ dWk,
                                               bf16* __restrict__ dWv, bf16* __restrict__ dWo)
{
    const int b = blockIdx.x;
    const float* src; bf16* dst; size_t off;
    if (b < 1024)      { src = Q;  dst = dQ;  off = (size_t)b * 4096; }
    else if (b < 2048) { src = K;  dst = dK;  off = (size_t)(b - 1024) * 4096; }
    else {
        const int wb = b - 2048, wi = wb >> 6;
        off = (size_t)(wb & 63) * 4096;
        src = wi == 0 ? Wq : wi == 1 ? Wk : wi == 2 ? Wv : Wo;
        dst = wi == 0 ? dWq : wi == 1 ? dWk : wi == 2 ? dWv : dWo;
    }
    const size_t p = off + threadIdx.x * 16;
    const float4 v0 = *(const float4*)(src + p);
    const float4 v1 = *(const float4*)(src + p + 4);
    const float4 v2 = *(const float4*)(src + p + 8);
    const float4 v3 = *(const float4*)(src + p + 12);
    uint4 o0, o1;
    o0.x = pack2(v0.x, v0.y); o0.y = pack2(v0.z, v0.w);
    o0.z = pack2(v1.x, v1.y); o0.w = pack2(v1.z, v1.w);
    o1.x = pack2(v2.x, v2.y); o1.y = pack2(v2.z, v2.w);
    o1.z = pack2(v3.x, v3.y); o1.w = pack2(v3.z, v3.w);
    *(uint4*)(dst + p)     = o0;
    *(uint4*)(dst + p + 8) = o1;
}

// ---------------------------------------------------------------------------
// Fused QKV projection GEMM (NT), 128x128 tiles, BK=64 single-buffered
// gll16 staging (8 iters, 2 barriers each), unpadded [128][64] LDS with
// granule swizzle LDS[row][g] = glob[row][g ^ (row&7)].
// Q/K-proj compute C^T (operand-swapped) so a lane's 4 acc regs are 4
// consecutive d -> uint2 stores; V-proj computes C normally (regs = 4
// consecutive n, contiguous in the [b,h,d,n] layout). Grid (64, 12).
// ---------------------------------------------------------------------------
__global__ __launch_bounds__(256) void gemm_qkv(const bf16* __restrict__ Aq, const bf16* __restrict__ Ak,
                                                const bf16* __restrict__ Wq, const bf16* __restrict__ Wk,
                                                const bf16* __restrict__ Wv,
                                                const float* __restrict__ bq, const float* __restrict__ bk,
                                                const float* __restrict__ bv,
                                                bf16* __restrict__ oQ, bf16* __restrict__ oK,
                                                bf16* __restrict__ oV)
{
    __shared__ bf16 Xs[128 * 64];
    __shared__ bf16 Ws[128 * 64];

    const int tid = threadIdx.x, lane = tid & 63, wave = tid >> 6;
    const int yy = blockIdx.y, wi = yy >> 2;
    const bf16* A     = wi == 0 ? Aq : Ak;
    const bf16* W     = wi == 0 ? Wq : wi == 1 ? Wk : Wv;
    const float* bias = wi == 0 ? bq : wi == 1 ? bk : bv;
    bf16* out         = wi == 0 ? oQ : wi == 1 ? oK : oV;
    const bool vmode  = (wi == 2);
    const int bm = blockIdx.x * 128;
    const int bn = (yy & 3) * 128;

    // staging: slot s = tid + 256c -> row (tid>>3)+32c, lds granule tid&7,
    // source granule (tid&7)^((tid>>3)&7)
    const int srow = tid >> 3;
    const int sg8  = (((tid & 7) ^ (srow & 7)) * 8);
    const int wm = (wave >> 1) * 64, wn = (wave & 1) * 64;
    const int fr = lane & 15, fq = lane >> 4;

    f32x4 acc[4][4] = {};
    const bf16* Ap = A + (size_t)(bm + srow) * 512 + sg8;
    const bf16* Wp = W + (size_t)(bn + srow) * 512 + sg8;
    const int ld = 8 * tid;

    for (int k0 = 0; k0 < 512; k0 += 64) {
        __syncthreads();
        #pragma unroll
        for (int c = 0; c < 4; c++) {
            gll16(Ap + k0 + (size_t)(32 * c) * 512, Xs + ld + 2048 * c);
            gll16(Wp + k0 + (size_t)(32 * c) * 512, Ws + ld + 2048 * c);
        }
        __syncthreads();

        #pragma unroll
        for (int c2 = 0; c2 < 2; c2++) {
            bf16x8 fx[4], fw[4];
            #pragma unroll
            for (int i = 0; i < 4; i++) {
                const int rx = wm + 16 * i + fr;
                const int rw = wn + 16 * i + fr;
                fx[i] = *(const bf16x8*)(&Xs[rx * 64 + (((c2 * 4 + fq) ^ (rx & 7)) * 8)]);
                fw[i] = *(const bf16x8*)(&Ws[rw * 64 + (((c2 * 4 + fq) ^ (rw & 7)) * 8)]);
            }
            if (vmode) {
                #pragma unroll
                for (int i = 0; i < 4; i++)
                    #pragma unroll
                    for (int j = 0; j < 4; j++)
                        acc[i][j] = __builtin_amdgcn_mfma_f32_16x16x32_bf16(fx[i], fw[j], acc[i][j], 0, 0, 0);
            } else {
                #pragma unroll
                for (int i = 0; i < 4; i++)
                    #pragma unroll
                    for (int j = 0; j < 4; j++)
                        acc[i][j] = __builtin_amdgcn_mfma_f32_16x16x32_bf16(fw[i], fx[j], acc[i][j], 0, 0, 0);
            }
        }
    }

    if (!vmode) {
        // C^T: acc[i][j] row = weight-col (d_full), col = data-row (n).
        // lane regs r -> 4 consecutive d. out[((b*8+h)*1024+n)*64+d]
        #pragma unroll
        for (int i = 0; i < 4; i++) {
            const int colb = bn + wn + 16 * i + 4 * fq;   // d_full base (mult of 4)
            const float4 b4 = *(const float4*)(bias + colb);
            const int h = colb >> 6, d0 = colb & 63;
            #pragma unroll
            for (int j = 0; j < 4; j++) {
                const int n = bm + wm + 16 * j + fr;
                const int b = n >> 10, nn = n & 1023;
                uint2 pk;
                pk.x = pack2(acc[i][j][0] + b4.x, acc[i][j][1] + b4.y);
                pk.y = pack2(acc[i][j][2] + b4.z, acc[i][j][3] + b4.w);
                *(uint2*)(out + ((size_t)(b * 8 + h) * 1024 + nn) * 64 + d0) = pk;
            }
        }
    } else {
        // C: acc[i][j] row = data-row (n), col = weight-col. regs = 4 consec n.
        // out[((b*8+h)*64+d)*1024+n]
        #pragma unroll
        for (int i = 0; i < 4; i++) {
            const int n0 = bm + wm + 16 * i + 4 * fq;     // mult of 4
            const int b = n0 >> 10, nn = n0 & 1023;
            #pragma unroll
            for (int j = 0; j < 4; j++) {
                const int col = bn + wn + 16 * j + fr;
                const float bv2 = bias[col];
                const int h = col >> 6, d = col & 63;
                uint2 pk;
                pk.x = pack2(acc[i][j][0] + bv2, acc[i][j][1] + bv2);
                pk.y = pack2(acc[i][j][2] + bv2, acc[i][j][3] + bv2);
                *(uint2*)(out + ((size_t)(b * 8 + h) * 64 + d) * 1024 + nn) = pk;
            }
        }
    }
}

// ---------------------------------------------------------------------------
// MFMA flash attention — S^T form, fixed-max softmax. 16 q-rows per wave,
// grid 1024 (64 bh x 16 q-blocks), 4 waves/block, LDS 25KB -> 4 blk/CU.
// Qh [b,h,n,64], Kh [b,h,m,64], VhT [b,h,d,m]. XCD-local bh grouping.
// ---------------------------------------------------------------------------
__global__ __launch_bounds__(256) void attn_mfma(const bf16* __restrict__ Qh,
                                                 const bf16* __restrict__ Kh,
                                                 const bf16* __restrict__ VhT,
                                                 bf16* __restrict__ Oc)
{
    __shared__ bf16 Ks[64 * 64];
    __shared__ bf16 Vs[64 * 64];
    __shared__ bf16 Ps[4][16 * 72];

    const int tid = threadIdx.x, lane = tid & 63, w = tid >> 6;
    const int id = blockIdx.x;
    const int bh = (id & 7) * 8 + (id >> 7);        // XCD-local bh grouping
    const int wq = ((id >> 3) & 15) * 64 + w * 16;  // wave's q-tile (16 rows)

    const bf16* Qb = Qh  + ((size_t)bh * 1024 + wq) * 64;
    const bf16* Kb = Kh  + (size_t)bh * 1024 * 64;
    const bf16* Vb = VhT + (size_t)bh * 64 * 1024;

    const int fl = lane & 15, fq = lane >> 4;
    const int flk = fl & 7;
    const int gA = (fq ^ flk) * 8;
    const int gB = ((4 | fq) ^ flk) * 8;

    bf16x8 qf[2];
    qf[0] = *(const bf16x8*)(Qb + fl * 64 + fq * 8);
    qf[1] = *(const bf16x8*)(Qb + fl * 64 + 32 + fq * 8);

    f32x4 o[4] = {};
    float lsum = 0.f;
    const float sc2 = 0.04419417382415922f * 1.4426950408889634f; // /sqrt(512)*log2e

    const int srow = tid >> 3;
    const int sg8  = (((tid & 7) ^ (srow & 7)) * 8);
    const bf16* KbR  = Kb + (size_t)srow * 64 + sg8;
    const bf16* VbR0 = Vb + (size_t)srow * 1024 + sg8;
    const bf16* VbR1 = Vb + (size_t)(srow + 32) * 1024 + sg8;
    const int ld = 8 * tid;

    for (int kt = 0; kt < 16; kt++) {
        const int m0 = kt * 64;
        __syncthreads();
        gll16(KbR + (size_t)m0 * 64,        Ks + ld);
        gll16(KbR + (size_t)(m0 + 32) * 64, Ks + 2048 + ld);
        gll16(VbR0 + m0,                    Vs + ld);
        gll16(VbR1 + m0,                    Vs + 2048 + ld);
        __syncthreads();

        // K fragments (full 64x64 K tile per wave)
        bf16x8 kf[4][2];
        #pragma unroll
        for (int tm = 0; tm < 4; tm++) {
            kf[tm][0] = *(const bf16x8*)(&Ks[(16 * tm + fl) * 64 + gA]);
            kf[tm][1] = *(const bf16x8*)(&Ks[(16 * tm + fl) * 64 + gB]);
        }

        f32x4 st[4] = {};
        #pragma unroll
        for (int tm = 0; tm < 4; tm++) {
            st[tm] = __builtin_amdgcn_mfma_f32_16x16x32_bf16(kf[tm][0], qf[0], st[tm], 0, 0, 0);
            st[tm] = __builtin_amdgcn_mfma_f32_16x16x32_bf16(kf[tm][1], qf[1], st[tm], 0, 0, 0);
        }
        #pragma unroll
        for (int tm = 0; tm < 4; tm++) {
            float p0 = __builtin_amdgcn_exp2f(st[tm][0] * sc2);
            float p1 = __builtin_amdgcn_exp2f(st[tm][1] * sc2);
            float p2 = __builtin_amdgcn_exp2f(st[tm][2] * sc2);
            float p3 = __builtin_amdgcn_exp2f(st[tm][3] * sc2);
            lsum += (p0 + p1) + (p2 + p3);
            uint2 pk;
            pk.x = pack2(p0, p1);
            pk.y = pack2(p2, p3);
            *(uint2*)(&Ps[w][fl * 72 + 16 * tm + fq * 4]) = pk;
        }

        // V^T fragments
        bf16x8 vf[4][2];
        #pragma unroll
        for (int jd = 0; jd < 4; jd++) {
            vf[jd][0] = *(const bf16x8*)(&Vs[(16 * jd + fl) * 64 + gA]);
            vf[jd][1] = *(const bf16x8*)(&Vs[(16 * jd + fl) * 64 + gB]);
        }
        bf16x8 pf0 = *(const bf16x8*)(&Ps[w][fl * 72 + fq * 8]);
        bf16x8 pf1 = *(const bf16x8*)(&Ps[w][fl * 72 + 32 + fq * 8]);
        #pragma unroll
        for (int jd = 0; jd < 4; jd++) {
            o[jd] = __builtin_amdgcn_mfma_f32_16x16x32_bf16(vf[jd][0], pf0, o[jd], 0, 0, 0);
            o[jd] = __builtin_amdgcn_mfma_f32_16x16x32_bf16(vf[jd][1], pf1, o[jd], 0, 0, 0);
        }
    }

    const int b = bh >> 3, h = bh & 7;
    float ls = lsum;
    ls += __shfl_xor(ls, 16);
    ls += __shfl_xor(ls, 32);
    const float linv = 1.f / ls;
    const size_t obase = ((size_t)(b * 1024 + wq + fl)) * 512 + h * 64;
    #pragma unroll
    for (int jd = 0; jd < 4; jd++) {
        const ushort4 qr = *(const ushort4*)(Qb + fl * 64 + 16 * jd + fq * 4);
        uint2 w2;
        w2.x = pack2(o[jd][0] * linv + bfu2f(qr.x), o[jd][1] * linv + bfu2f(qr.y));
        w2.y = pack2(o[jd][2] * linv + bfu2f(qr.z), o[jd][3] * linv + bfu2f(qr.w));
        *(uint2*)(&Oc[obase + 16 * jd + fq * 4]) = w2;
    }
}

// ---------------------------------------------------------------------------
// LayerNorm over rows of 512 — wave/row, 8 consecutive elems/lane.
// ---------------------------------------------------------------------------
__global__ __launch_bounds__(256) void ln0(const bf16* __restrict__ X,
                                           const float* __restrict__ g,
                                           const float* __restrict__ be,
                                           bf16* __restrict__ Y)
{
    const int lane = threadIdx.x & 63;
    const int row = blockIdx.x * 4 + (threadIdx.x >> 6);
    const size_t base = (size_t)row * 512 + lane * 8;
    const bf16x8 xv = *(const bf16x8*)(X + base);
    float x[8];
    #pragma unroll
    for (int j = 0; j < 8; j++) x[j] = bfu2f((unsigned short)xv[j]);
    float s = 0.f, s2 = 0.f;
    #pragma unroll
    for (int j = 0; j < 8; j++) { s += x[j]; s2 += x[j] * x[j]; }
    s = wave_sum(s); s2 = wave_sum(s2);
    const float mean = s * (1.f / 512.f);
    const float var = s2 * (1.f / 512.f) - mean * mean;
    const float rs = rsqrtf(fmaxf(var, 0.f) + 1e-5f);
    const float4 gv0 = *(const float4*)(g + lane * 8);
    const float4 gv1 = *(const float4*)(g + lane * 8 + 4);
    const float4 bv0 = *(const float4*)(be + lane * 8);
    const float4 bv1 = *(const float4*)(be + lane * 8 + 4);
    uint4 ov;
    ov.x = pack2((x[0]-mean)*rs*gv0.x + bv0.x, (x[1]-mean)*rs*gv0.y + bv0.y);
    ov.y = pack2((x[2]-mean)*rs*gv0.z + bv0.z, (x[3]-mean)*rs*gv0.w + bv0.w);
    ov.z = pack2((x[4]-mean)*rs*gv1.x + bv1.x, (x[5]-mean)*rs*gv1.y + bv1.y);
    ov.w = pack2((x[6]-mean)*rs*gv1.z + bv1.z, (x[7]-mean)*rs*gv1.w + bv1.w);
    *(uint4*)(Y + base) = ov;
}

// ---------------------------------------------------------------------------
// FUSED O-projection + residual-relu + LayerNorm1 -> fp32 output.
// 256 blocks x 512 threads (8 waves). Block = 32 rows x ALL 512 cols, so the
// LN1 row-reduction is block-local and the residual R(n,j) is read from the
// resident A panel in LDS (A = ln0 output = R; K = 512 = full feature dim).
// A staged ONCE (32x512, 32KB, granule-swizzled); W staged per-64-K chunk
// (512x64, 64KB). Wave w owns cols [w*64, w*64+64): acc[4][2] (C^T form).
// Epilogue: y = R + relu(X + bo); cross-wave LDS reduce for mu/var; write
// fp32 out. Eliminates ln1 kernel + X round-trip + R re-read.
// LDS: 32 + 64 + 2 = 98KB -> 1 block/CU (grid 256 = exactly 1 per CU).
// ---------------------------------------------------------------------------
__global__ __launch_bounds__(512) void gemm_fo_ln1(const bf16* __restrict__ A,
                                                   const bf16* __restrict__ W,
                                                   const float* __restrict__ bo,
                                                   const float* __restrict__ g1,
                                                   const float* __restrict__ be1,
                                                   float* __restrict__ out)
{
    __shared__ bf16 As[32 * 512];
    __shared__ bf16 Ws[512 * 64];
    __shared__ float2 red[32][8];

    const int tid = threadIdx.x, lane = tid & 63, w = tid >> 6;
    const int bm = blockIdx.x * 32;
    const int wn = w * 64;
    const int fr = lane & 15, fq = lane >> 4;

    // ---- stage A rows [bm, bm+32) full-K, once. LDS[row][g]=glob[row][g^(row&7)]
    const int ldb = 8 * tid;
    #pragma unroll
    for (int c = 0; c < 4; c++) {
        const int lin = tid + 512 * c;       // granule id: row = lin>>6, g = lin&63
        const int row = lin >> 6, g = lin & 63;
        gll16(A + (size_t)(bm + row) * 512 + ((g ^ (row & 7)) * 8),
              As + ldb + 4096 * c);
    }

    // W staging indices (rows = output cols j; 8 rounds of 64 rows)
    const int srow = tid >> 3;
    const int sg8  = (((tid & 7) ^ (srow & 7)) * 8);
    const bf16* Wp = W + (size_t)srow * 512 + sg8;

    f32x4 acc[4][2] = {};   // [i: col-tile][j: row-tile]

    for (int kt = 0; kt < 8; kt++) {
        const int k0 = kt * 64;
        if (kt) __syncthreads();
        #pragma unroll
        for (int c = 0; c < 8; c++)
            gll16(Wp + k0 + (size_t)(64 * c) * 512, Ws + ldb + 4096 * c);
        __syncthreads();   // drains W gll16 (and A on first iter)

        const int kb = kt * 8;
        #pragma unroll
        for (int c2 = 0; c2 < 2; c2++) {
            bf16x8 fx[2], fw[4];
            #pragma unroll
            for (int j = 0; j < 2; j++) {
                const int rx = 16 * j + fr;
                fx[j] = *(const bf16x8*)(&As[rx * 512 + (kb + ((c2 * 4 + fq) ^ (rx & 7))) * 8]);
            }
            #pragma unroll
            for (int i = 0; i < 4; i++) {
                const int rw = wn + 16 * i + fr;
                fw[i] = *(const bf16x8*)(&Ws[rw * 64 + (((c2 * 4 + fq) ^ (rw & 7)) * 8)]);
            }
            #pragma unroll
            for (int i = 0; i < 4; i++)
                #pragma unroll
                for (int j = 0; j < 2; j++)
                    acc[i][j] = __builtin_amdgcn_mfma_f32_16x16x32_bf16(fw[i], fx[j], acc[i][j], 0, 0, 0);
        }
    }

    // ---- epilogue: y = R + relu(X + bo), then block LN over each row ----
    float yv[4][2][4];
    float s[2] = {0.f, 0.f}, s2[2] = {0.f, 0.f};
    #pragma unroll
    for (int i = 0; i < 4; i++) {
        const int c = wn + 16 * i + 4 * fq;          // output col base (mult of 4)
        const float4 bo4 = *(const float4*)(bo + c);
        const int gc = c >> 3, co = c & 7;           // granule + in-granule offset
        #pragma unroll
        for (int j = 0; j < 2; j++) {
            const int n = 16 * j + fr;               // local row
            const ushort4 rr = *(const ushort4*)(&As[n * 512 + ((gc ^ (n & 7)) * 8 + co)]);
            float y0 = bfu2f(rr.x) + fmaxf(acc[i][j][0] + bo4.x, 0.f);
            float y1 = bfu2f(rr.y) + fmaxf(acc[i][j][1] + bo4.y, 0.f);
            float y2 = bfu2f(rr.z) + fmaxf(acc[i][j][2] + bo4.z, 0.f);
            float y3 = bfu2f(rr.w) + fmaxf(acc[i][j][3] + bo4.w, 0.f);
            s[j]  += (y0 + y1) + (y2 + y3);
            s2[j] += (y0 * y0 + y1 * y1) + (y2 * y2 + y3 * y3);
            yv[i][j][0] = y0; yv[i][j][1] = y1; yv[i][j][2] = y2; yv[i][j][3] = y3;
        }
    }
    // reduce over fq (4 lanes share a row within the wave)
    #pragma unroll
    for (int j = 0; j < 2; j++) {
        s[j]  += __shfl_xor(s[j], 16);  s[j]  += __shfl_xor(s[j], 32);
        s2[j] += __shfl_xor(s2[j], 16); s2[j] += __shfl_xor(s2[j], 32);
    }
    if (fq == 0) {
        red[fr][w]      = make_float2(s[0], s2[0]);
        red[16 + fr][w] = make_float2(s[1], s2[1]);
    }
    __syncthreads();
    float mu[2], rs[2];
    #pragma unroll
    for (int j = 0; j < 2; j++) {
        const int n = 16 * j + fr;
        float S = 0.f, S2 = 0.f;
        #pragma unroll
        for (int q = 0; q < 8; q++) { const float2 v = red[n][q]; S += v.x; S2 += v.y; }
        mu[j] = S * (1.f / 512.f);
        const float var = S2 * (1.f / 512.f) - mu[j] * mu[j];
        rs[j] = rsqrtf(fmaxf(var, 0.f) + 1e-5f);
    }
    #pragma unroll
    for (int i = 0; i < 4; i++) {
        const int c = wn + 16 * i + 4 * fq;
        const float4 g4 = *(const float4*)(g1 + c);
        const float4 b4 = *(const float4*)(be1 + c);
        #pragma unroll
        for (int j = 0; j < 2; j++) {
            const int n = bm + 16 * j + fr;
            float4 o4;
            o4.x = (yv[i][j][0] - mu[j]) * rs[j] * g4.x + b4.x;
            o4.y = (yv[i][j][1] - mu[j]) * rs[j] * g4.y + b4.y;
            o4.z = (yv[i][j][2] - mu[j]) * rs[j] * g4.z + b4.z;
            o4.w = (yv[i][j][3] - mu[j]) * rs[j] * g4.w + b4.w;
            *(float4*)(out + (size_t)n * 512 + c) = o4;
        }
    }
}

// ---------------------------------------------------------------------------
extern "C" void kernel_launch(void* const* d_in, const int* in_sizes, int n_in,
                              void* d_out, int out_size, void* d_ws, size_t ws_size,
                              hipStream_t stream)
{
    const float* Q   = (const float*)d_in[0];
    const float* K   = (const float*)d_in[1];
    const float* Wq  = (const float*)d_in[2];
    const float* bq  = (const float*)d_in[3];
    const float* Wk  = (const float*)d_in[4];
    const float* bk  = (const float*)d_in[5];
    const float* Wv  = (const float*)d_in[6];
    const float* bv  = (const float*)d_in[7];
    const float* Wo  = (const float*)d_in[8];
    const float* bo  = (const float*)d_in[9];
    const float* g0  = (const float*)d_in[10];
    const float* be0 = (const float*)d_in[11];
    const float* g1  = (const float*)d_in[12];
    const float* be1 = (const float*)d_in[13];
    float* out = (float*)d_out;

    const size_t NQK = (size_t)8 * 1024 * 512;  // 4M
    const size_t NW  = (size_t)512 * 512;       // 256K
    bf16* ws   = (bf16*)d_ws;
    bf16* cQ   = ws;
    bf16* cK   = cQ + NQK;
    bf16* cWq  = cK + NQK;
    bf16* cWk  = cWq + NW;
    bf16* cWv  = cWk + NW;
    bf16* cWo  = cWv + NW;
    bf16* pQh  = cWo + NW;           // [b,h,n,d]
    bf16* pKh  = pQh + NQK;          // [b,h,m,d]
    bf16* pVhT = pKh + NQK;          // [b,h,d,m]
    bf16* pOc  = (bf16*)d_out;       // attn output staged in d_out
    bf16* pO1  = pKh;                // Kh dead after attn

    castall<<<2304, 256, 0, stream>>>(Q, K, Wq, Wk, Wv, Wo, cQ, cK, cWq, cWk, cWv, cWo);
    gemm_qkv<<<dim3(64, 12), 256, 0, stream>>>(cQ, cK, cWq, cWk, cWv, bq, bk, bv, pQh, pKh, pVhT);
    attn_mfma<<<1024, 256, 0, stream>>>(pQh, pKh, pVhT, pOc);
    ln0<<<2048, 256, 0, stream>>>(pOc, g0, be0, pO1);
    gemm_fo_ln1<<<256, 512, 0, stream>>>(pO1, cWo, bo, g1, be1, out);
}

// Round 6
// 184.469 us; speedup vs baseline: 1.0585x; 1.0097x over previous
//
#include <hip/hip_runtime.h>
#include <hip/hip_bf16.h>

typedef __hip_bfloat16 bf16;
typedef short bf16x8 __attribute__((ext_vector_type(8)));
typedef float f32x4 __attribute__((ext_vector_type(4)));
typedef unsigned int u32;

static __device__ __forceinline__ float bfu2f(unsigned short u) { return __uint_as_float((u32)u << 16); }
static __device__ __forceinline__ u32 pack2(float a, float b) {
    return (u32)__bfloat16_as_ushort(__float2bfloat16(a))
         | ((u32)__bfloat16_as_ushort(__float2bfloat16(b)) << 16);
}

// async global->LDS 16B copy (wave-uniform LDS base + lane*16 by HW).
static __device__ __forceinline__ void gll16(const bf16* g, bf16* l) {
    __builtin_amdgcn_global_load_lds((const __attribute__((address_space(1))) void*)g,
                                     (__attribute__((address_space(3))) void*)l,
                                     16, 0, 0);
}

// ---------------------------------------------------------------------------
// Fused QKV projection GEMM (NT), 128x128 tiles, BK=64, reads fp32 A/W
// DIRECTLY (castall kernel eliminated): per-granule reg-staging
// {2x float4 load -> pack2 -> ds_write_b128} into the SAME swizzled LDS
// layout as before (LDS[row][g] = glob[row][g ^ (row&7)]), so the MFMA
// core and C-write epilogues are unchanged. Grid (64, 12).
// ---------------------------------------------------------------------------
__global__ __launch_bounds__(256) void gemm_qkv(const float* __restrict__ Aq, const float* __restrict__ Ak,
                                                const float* __restrict__ Wq, const float* __restrict__ Wk,
                                                const float* __restrict__ Wv,
                                                const float* __restrict__ bq, const float* __restrict__ bk,
                                                const float* __restrict__ bv,
                                                bf16* __restrict__ oQ, bf16* __restrict__ oK,
                                                bf16* __restrict__ oV)
{
    __shared__ bf16 Xs[128 * 64];
    __shared__ bf16 Ws[128 * 64];

    const int tid = threadIdx.x, lane = tid & 63, wave = tid >> 6;
    const int yy = blockIdx.y, wi = yy >> 2;
    const float* A    = wi == 0 ? Aq : Ak;
    const float* W    = wi == 0 ? Wq : wi == 1 ? Wk : Wv;
    const float* bias = wi == 0 ? bq : wi == 1 ? bk : bv;
    bf16* out         = wi == 0 ? oQ : wi == 1 ? oK : oV;
    const bool vmode  = (wi == 2);
    const int bm = blockIdx.x * 128;
    const int bn = (yy & 3) * 128;

    const int srow = tid >> 3;
    const int sg8  = (((tid & 7) ^ (srow & 7)) * 8);
    const int wm = (wave >> 1) * 64, wn = (wave & 1) * 64;
    const int fr = lane & 15, fq = lane >> 4;

    f32x4 acc[4][4] = {};
    const float* Ap = A + (size_t)(bm + srow) * 512 + sg8;
    const float* Wp = W + (size_t)(bn + srow) * 512 + sg8;
    const int ld = 8 * tid;

    for (int k0 = 0; k0 < 512; k0 += 64) {
        __syncthreads();
        // reg-stage fp32 -> bf16 into LDS, 2 c-granules per batch (reg pressure)
        #pragma unroll
        for (int cb = 0; cb < 2; cb++) {
            float4 ab[2][2], wb[2][2];
            #pragma unroll
            for (int c = 0; c < 2; c++) {
                const float* ap = Ap + k0 + (size_t)(32 * (2 * cb + c)) * 512;
                const float* wp = Wp + k0 + (size_t)(32 * (2 * cb + c)) * 512;
                ab[c][0] = *(const float4*)(ap); ab[c][1] = *(const float4*)(ap + 4);
                wb[c][0] = *(const float4*)(wp); wb[c][1] = *(const float4*)(wp + 4);
            }
            #pragma unroll
            for (int c = 0; c < 2; c++) {
                uint4 av, wv;
                av.x = pack2(ab[c][0].x, ab[c][0].y); av.y = pack2(ab[c][0].z, ab[c][0].w);
                av.z = pack2(ab[c][1].x, ab[c][1].y); av.w = pack2(ab[c][1].z, ab[c][1].w);
                wv.x = pack2(wb[c][0].x, wb[c][0].y); wv.y = pack2(wb[c][0].z, wb[c][0].w);
                wv.z = pack2(wb[c][1].x, wb[c][1].y); wv.w = pack2(wb[c][1].z, wb[c][1].w);
                *(uint4*)(Xs + ld + 2048 * (2 * cb + c)) = av;
                *(uint4*)(Ws + ld + 2048 * (2 * cb + c)) = wv;
            }
        }
        __syncthreads();

        #pragma unroll
        for (int c2 = 0; c2 < 2; c2++) {
            bf16x8 fx[4], fw[4];
            #pragma unroll
            for (int i = 0; i < 4; i++) {
                const int rx = wm + 16 * i + fr;
                const int rw = wn + 16 * i + fr;
                fx[i] = *(const bf16x8*)(&Xs[rx * 64 + (((c2 * 4 + fq) ^ (rx & 7)) * 8)]);
                fw[i] = *(const bf16x8*)(&Ws[rw * 64 + (((c2 * 4 + fq) ^ (rw & 7)) * 8)]);
            }
            if (vmode) {
                #pragma unroll
                for (int i = 0; i < 4; i++)
                    #pragma unroll
                    for (int j = 0; j < 4; j++)
                        acc[i][j] = __builtin_amdgcn_mfma_f32_16x16x32_bf16(fx[i], fw[j], acc[i][j], 0, 0, 0);
            } else {
                #pragma unroll
                for (int i = 0; i < 4; i++)
                    #pragma unroll
                    for (int j = 0; j < 4; j++)
                        acc[i][j] = __builtin_amdgcn_mfma_f32_16x16x32_bf16(fw[i], fx[j], acc[i][j], 0, 0, 0);
            }
        }
    }

    if (!vmode) {
        // C^T: acc[i][j] row = weight-col (d_full), col = data-row (n).
        #pragma unroll
        for (int i = 0; i < 4; i++) {
            const int colb = bn + wn + 16 * i + 4 * fq;
            const float4 b4 = *(const float4*)(bias + colb);
            const int h = colb >> 6, d0 = colb & 63;
            #pragma unroll
            for (int j = 0; j < 4; j++) {
                const int n = bm + wm + 16 * j + fr;
                const int b = n >> 10, nn = n & 1023;
                uint2 pk;
                pk.x = pack2(acc[i][j][0] + b4.x, acc[i][j][1] + b4.y);
                pk.y = pack2(acc[i][j][2] + b4.z, acc[i][j][3] + b4.w);
                *(uint2*)(out + ((size_t)(b * 8 + h) * 1024 + nn) * 64 + d0) = pk;
            }
        }
    } else {
        // C: acc[i][j] row = data-row (n), col = weight-col.
        #pragma unroll
        for (int i = 0; i < 4; i++) {
            const int n0 = bm + wm + 16 * i + 4 * fq;
            const int b = n0 >> 10, nn = n0 & 1023;
            #pragma unroll
            for (int j = 0; j < 4; j++) {
                const int col = bn + wn + 16 * j + fr;
                const float bv2 = bias[col];
                const int h = col >> 6, d = col & 63;
                uint2 pk;
                pk.x = pack2(acc[i][j][0] + bv2, acc[i][j][1] + bv2);
                pk.y = pack2(acc[i][j][2] + bv2, acc[i][j][3] + bv2);
                *(uint2*)(out + ((size_t)(b * 8 + h) * 64 + d) * 1024 + nn) = pk;
            }
        }
    }
}

// ---------------------------------------------------------------------------
// MFMA flash attention — S^T form, fixed-max softmax. 16 q-rows per wave,
// grid 1024 (64 bh x 16 q-blocks), 4 waves/block, LDS 25KB -> 4 blk/CU.
// Qh [b,h,n,64], Kh [b,h,m,64], VhT [b,h,d,m]. XCD-local bh grouping.
// Output now goes to WORKSPACE (pOc) because the fused epilogue kernel
// reads it while writing fp32 to d_out (overlap race otherwise).
// ---------------------------------------------------------------------------
__global__ __launch_bounds__(256) void attn_mfma(const bf16* __restrict__ Qh,
                                                 const bf16* __restrict__ Kh,
                                                 const bf16* __restrict__ VhT,
                                                 bf16* __restrict__ Oc)
{
    __shared__ bf16 Ks[64 * 64];
    __shared__ bf16 Vs[64 * 64];
    __shared__ bf16 Ps[4][16 * 72];

    const int tid = threadIdx.x, lane = tid & 63, w = tid >> 6;
    const int id = blockIdx.x;
    const int bh = (id & 7) * 8 + (id >> 7);        // XCD-local bh grouping
    const int wq = ((id >> 3) & 15) * 64 + w * 16;  // wave's q-tile (16 rows)

    const bf16* Qb = Qh  + ((size_t)bh * 1024 + wq) * 64;
    const bf16* Kb = Kh  + (size_t)bh * 1024 * 64;
    const bf16* Vb = VhT + (size_t)bh * 64 * 1024;

    const int fl = lane & 15, fq = lane >> 4;
    const int flk = fl & 7;
    const int gA = (fq ^ flk) * 8;
    const int gB = ((4 | fq) ^ flk) * 8;

    bf16x8 qf[2];
    qf[0] = *(const bf16x8*)(Qb + fl * 64 + fq * 8);
    qf[1] = *(const bf16x8*)(Qb + fl * 64 + 32 + fq * 8);

    f32x4 o[4] = {};
    float lsum = 0.f;
    const float sc2 = 0.04419417382415922f * 1.4426950408889634f; // /sqrt(512)*log2e

    const int srow = tid >> 3;
    const int sg8  = (((tid & 7) ^ (srow & 7)) * 8);
    const bf16* KbR  = Kb + (size_t)srow * 64 + sg8;
    const bf16* VbR0 = Vb + (size_t)srow * 1024 + sg8;
    const bf16* VbR1 = Vb + (size_t)(srow + 32) * 1024 + sg8;
    const int ld = 8 * tid;

    for (int kt = 0; kt < 16; kt++) {
        const int m0 = kt * 64;
        __syncthreads();
        gll16(KbR + (size_t)m0 * 64,        Ks + ld);
        gll16(KbR + (size_t)(m0 + 32) * 64, Ks + 2048 + ld);
        gll16(VbR0 + m0,                    Vs + ld);
        gll16(VbR1 + m0,                    Vs + 2048 + ld);
        __syncthreads();

        bf16x8 kf[4][2];
        #pragma unroll
        for (int tm = 0; tm < 4; tm++) {
            kf[tm][0] = *(const bf16x8*)(&Ks[(16 * tm + fl) * 64 + gA]);
            kf[tm][1] = *(const bf16x8*)(&Ks[(16 * tm + fl) * 64 + gB]);
        }

        f32x4 st[4] = {};
        #pragma unroll
        for (int tm = 0; tm < 4; tm++) {
            st[tm] = __builtin_amdgcn_mfma_f32_16x16x32_bf16(kf[tm][0], qf[0], st[tm], 0, 0, 0);
            st[tm] = __builtin_amdgcn_mfma_f32_16x16x32_bf16(kf[tm][1], qf[1], st[tm], 0, 0, 0);
        }
        #pragma unroll
        for (int tm = 0; tm < 4; tm++) {
            float p0 = __builtin_amdgcn_exp2f(st[tm][0] * sc2);
            float p1 = __builtin_amdgcn_exp2f(st[tm][1] * sc2);
            float p2 = __builtin_amdgcn_exp2f(st[tm][2] * sc2);
            float p3 = __builtin_amdgcn_exp2f(st[tm][3] * sc2);
            lsum += (p0 + p1) + (p2 + p3);
            uint2 pk;
            pk.x = pack2(p0, p1);
            pk.y = pack2(p2, p3);
            *(uint2*)(&Ps[w][fl * 72 + 16 * tm + fq * 4]) = pk;
        }

        bf16x8 vf[4][2];
        #pragma unroll
        for (int jd = 0; jd < 4; jd++) {
            vf[jd][0] = *(const bf16x8*)(&Vs[(16 * jd + fl) * 64 + gA]);
            vf[jd][1] = *(const bf16x8*)(&Vs[(16 * jd + fl) * 64 + gB]);
        }
        bf16x8 pf0 = *(const bf16x8*)(&Ps[w][fl * 72 + fq * 8]);
        bf16x8 pf1 = *(const bf16x8*)(&Ps[w][fl * 72 + 32 + fq * 8]);
        #pragma unroll
        for (int jd = 0; jd < 4; jd++) {
            o[jd] = __builtin_amdgcn_mfma_f32_16x16x32_bf16(vf[jd][0], pf0, o[jd], 0, 0, 0);
            o[jd] = __builtin_amdgcn_mfma_f32_16x16x32_bf16(vf[jd][1], pf1, o[jd], 0, 0, 0);
        }
    }

    const int b = bh >> 3, h = bh & 7;
    float ls = lsum;
    ls += __shfl_xor(ls, 16);
    ls += __shfl_xor(ls, 32);
    const float linv = 1.f / ls;
    const size_t obase = ((size_t)(b * 1024 + wq + fl)) * 512 + h * 64;
    #pragma unroll
    for (int jd = 0; jd < 4; jd++) {
        const ushort4 qr = *(const ushort4*)(Qb + fl * 64 + 16 * jd + fq * 4);
        uint2 w2;
        w2.x = pack2(o[jd][0] * linv + bfu2f(qr.x), o[jd][1] * linv + bfu2f(qr.y));
        w2.y = pack2(o[jd][2] * linv + bfu2f(qr.z), o[jd][3] * linv + bfu2f(qr.w));
        *(uint2*)(&Oc[obase + 16 * jd + fq * 4]) = w2;
    }
}

// ---------------------------------------------------------------------------
// FUSED LayerNorm0 + O-projection + residual-relu + LayerNorm1 -> fp32 out.
// 256 blocks x 512 threads (8 waves). Block = 32 rows x ALL 512 cols.
// Phase 1: stage attn-out rows via gll16 (granule-swizzled), barrier.
// Phase 2: ln0 IN PLACE on the LDS panel — 16 threads/row butterfly stats,
//          normalize + rewrite bf16 (same rounding as the old ln0 kernel).
//          The normalized panel is both the GEMM A-input AND the residual.
// Phase 3: GEMM over W chunks; W read from fp32 Wo (castall eliminated):
//          reg-stage {2x float4 -> pack2 -> ds_write_b128}, same swizzle.
// Phase 4: y = R + relu(X + bo); cross-wave LDS reduce; ln1; fp32 out.
// LDS: 32 + 64 + 2 = 98KB -> 1 block/CU.
// ---------------------------------------------------------------------------
__global__ __launch_bounds__(512) void gemm_fo_ln1(const bf16* __restrict__ A,
                                                   const float* __restrict__ Wo,
                                                   const float* __restrict__ g0,
                                                   const float* __restrict__ be0,
                                                   const float* __restrict__ bo,
                                                   const float* __restrict__ g1,
                                                   const float* __restrict__ be1,
                                                   float* __restrict__ out)
{
    __shared__ bf16 As[32 * 512];
    __shared__ bf16 Ws[512 * 64];
    __shared__ float2 red[32][8];

    const int tid = threadIdx.x, lane = tid & 63, w = tid >> 6;
    const int bm = blockIdx.x * 32;
    const int wn = w * 64;
    const int fr = lane & 15, fq = lane >> 4;

    // ---- Phase 1: stage A rows [bm, bm+32), granule-swizzled --------------
    const int ldb = 8 * tid;
    #pragma unroll
    for (int c = 0; c < 4; c++) {
        const int lin = tid + 512 * c;
        const int row = lin >> 6, g = lin & 63;
        gll16(A + (size_t)(bm + row) * 512 + ((g ^ (row & 7)) * 8),
              As + ldb + 4096 * c);
    }
    __syncthreads();   // A panel resident

    // ---- Phase 2: ln0 in place (row r: 16 threads x 32 cols each) ---------
    {
        const int r = tid >> 4, ci = tid & 15;
        const int lrow = r * 512;
        const int rx = (r & 7) * 8;
        float xv[4][8];
        float s = 0.f, s2 = 0.f;
        #pragma unroll
        for (int gg = 0; gg < 4; gg++) {
            const int g = ci * 4 + gg;
            const bf16x8 v = *(const bf16x8*)(&As[lrow + ((g * 8) ^ rx)]);
            #pragma unroll
            for (int e = 0; e < 8; e++) {
                const float f = bfu2f((unsigned short)v[e]);
                xv[gg][e] = f; s += f; s2 += f * f;
            }
        }
        #pragma unroll
        for (int off = 1; off < 16; off <<= 1) {
            s += __shfl_xor(s, off); s2 += __shfl_xor(s2, off);
        }
        const float mu  = s * (1.f / 512.f);
        const float var = s2 * (1.f / 512.f) - mu * mu;
        const float rs0 = rsqrtf(fmaxf(var, 0.f) + 1e-5f);
        #pragma unroll
        for (int gg = 0; gg < 4; gg++) {
            const int g = ci * 4 + gg;
            const float4 gv0 = *(const float4*)(g0 + g * 8);
            const float4 gv1 = *(const float4*)(g0 + g * 8 + 4);
            const float4 bv0 = *(const float4*)(be0 + g * 8);
            const float4 bv1 = *(const float4*)(be0 + g * 8 + 4);
            uint4 ov;
            ov.x = pack2((xv[gg][0]-mu)*rs0*gv0.x + bv0.x, (xv[gg][1]-mu)*rs0*gv0.y + bv0.y);
            ov.y = pack2((xv[gg][2]-mu)*rs0*gv0.z + bv0.z, (xv[gg][3]-mu)*rs0*gv0.w + bv0.w);
            ov.z = pack2((xv[gg][4]-mu)*rs0*gv1.x + bv1.x, (xv[gg][5]-mu)*rs0*gv1.y + bv1.y);
            ov.w = pack2((xv[gg][6]-mu)*rs0*gv1.z + bv1.z, (xv[gg][7]-mu)*rs0*gv1.w + bv1.w);
            *(uint4*)(&As[lrow + ((g * 8) ^ rx)]) = ov;
        }
    }
    __syncthreads();   // normalized panel visible to all

    // ---- Phase 3: GEMM over W chunks (fp32 Wo, reg-staged) ----------------
    const int srow = tid >> 3;
    const int sg8  = (((tid & 7) ^ (srow & 7)) * 8);
    const float* Wp = Wo + (size_t)srow * 512 + sg8;

    f32x4 acc[4][2] = {};

    for (int kt = 0; kt < 8; kt++) {
        const int k0 = kt * 64;
        if (kt) __syncthreads();
        #pragma unroll
        for (int cb = 0; cb < 2; cb++) {
            float4 wb[4][2];
            #pragma unroll
            for (int c = 0; c < 4; c++) {
                const float* wp = Wp + k0 + (size_t)(64 * (4 * cb + c)) * 512;
                wb[c][0] = *(const float4*)(wp); wb[c][1] = *(const float4*)(wp + 4);
            }
            #pragma unroll
            for (int c = 0; c < 4; c++) {
                uint4 wv;
                wv.x = pack2(wb[c][0].x, wb[c][0].y); wv.y = pack2(wb[c][0].z, wb[c][0].w);
                wv.z = pack2(wb[c][1].x, wb[c][1].y); wv.w = pack2(wb[c][1].z, wb[c][1].w);
                *(uint4*)(Ws + ldb + 4096 * (4 * cb + c)) = wv;
            }
        }
        __syncthreads();

        const int kb = kt * 8;
        #pragma unroll
        for (int c2 = 0; c2 < 2; c2++) {
            bf16x8 fx[2], fw[4];
            #pragma unroll
            for (int j = 0; j < 2; j++) {
                const int rx = 16 * j + fr;
                fx[j] = *(const bf16x8*)(&As[rx * 512 + (kb + ((c2 * 4 + fq) ^ (rx & 7))) * 8]);
            }
            #pragma unroll
            for (int i = 0; i < 4; i++) {
                const int rw = wn + 16 * i + fr;
                fw[i] = *(const bf16x8*)(&Ws[rw * 64 + (((c2 * 4 + fq) ^ (rw & 7)) * 8)]);
            }
            #pragma unroll
            for (int i = 0; i < 4; i++)
                #pragma unroll
                for (int j = 0; j < 2; j++)
                    acc[i][j] = __builtin_amdgcn_mfma_f32_16x16x32_bf16(fw[i], fx[j], acc[i][j], 0, 0, 0);
        }
    }

    // ---- Phase 4: y = R + relu(X + bo), block LN1, fp32 store -------------
    float yv[4][2][4];
    float s[2] = {0.f, 0.f}, s2[2] = {0.f, 0.f};
    #pragma unroll
    for (int i = 0; i < 4; i++) {
        const int c = wn + 16 * i + 4 * fq;
        const float4 bo4 = *(const float4*)(bo + c);
        const int gc = c >> 3, co = c & 7;
        #pragma unroll
        for (int j = 0; j < 2; j++) {
            const int n = 16 * j + fr;
            const ushort4 rr = *(const ushort4*)(&As[n * 512 + ((gc ^ (n & 7)) * 8 + co)]);
            float y0 = bfu2f(rr.x) + fmaxf(acc[i][j][0] + bo4.x, 0.f);
            float y1 = bfu2f(rr.y) + fmaxf(acc[i][j][1] + bo4.y, 0.f);
            float y2 = bfu2f(rr.z) + fmaxf(acc[i][j][2] + bo4.z, 0.f);
            float y3 = bfu2f(rr.w) + fmaxf(acc[i][j][3] + bo4.w, 0.f);
            s[j]  += (y0 + y1) + (y2 + y3);
            s2[j] += (y0 * y0 + y1 * y1) + (y2 * y2 + y3 * y3);
            yv[i][j][0] = y0; yv[i][j][1] = y1; yv[i][j][2] = y2; yv[i][j][3] = y3;
        }
    }
    #pragma unroll
    for (int j = 0; j < 2; j++) {
        s[j]  += __shfl_xor(s[j], 16);  s[j]  += __shfl_xor(s[j], 32);
        s2[j] += __shfl_xor(s2[j], 16); s2[j] += __shfl_xor(s2[j], 32);
    }
    if (fq == 0) {
        red[fr][w]      = make_float2(s[0], s2[0]);
        red[16 + fr][w] = make_float2(s[1], s2[1]);
    }
    __syncthreads();
    float mu[2], rs[2];
    #pragma unroll
    for (int j = 0; j < 2; j++) {
        const int n = 16 * j + fr;
        float S = 0.f, S2 = 0.f;
        #pragma unroll
        for (int q = 0; q < 8; q++) { const float2 v = red[n][q]; S += v.x; S2 += v.y; }
        mu[j] = S * (1.f / 512.f);
        const float var = S2 * (1.f / 512.f) - mu[j] * mu[j];
        rs[j] = rsqrtf(fmaxf(var, 0.f) + 1e-5f);
    }
    #pragma unroll
    for (int i = 0; i < 4; i++) {
        const int c = wn + 16 * i + 4 * fq;
        const float4 g4 = *(const float4*)(g1 + c);
        const float4 b4 = *(const float4*)(be1 + c);
        #pragma unroll
        for (int j = 0; j < 2; j++) {
            const int n = bm + 16 * j + fr;
            float4 o4;
            o4.x = (yv[i][j][0] - mu[j]) * rs[j] * g4.x + b4.x;
            o4.y = (yv[i][j][1] - mu[j]) * rs[j] * g4.y + b4.y;
            o4.z = (yv[i][j][2] - mu[j]) * rs[j] * g4.z + b4.z;
            o4.w = (yv[i][j][3] - mu[j]) * rs[j] * g4.w + b4.w;
            *(float4*)(out + (size_t)n * 512 + c) = o4;
        }
    }
}

// ---------------------------------------------------------------------------
extern "C" void kernel_launch(void* const* d_in, const int* in_sizes, int n_in,
                              void* d_out, int out_size, void* d_ws, size_t ws_size,
                              hipStream_t stream)
{
    const float* Q   = (const float*)d_in[0];
    const float* K   = (const float*)d_in[1];
    const float* Wq  = (const float*)d_in[2];
    const float* bq  = (const float*)d_in[3];
    const float* Wk  = (const float*)d_in[4];
    const float* bk  = (const float*)d_in[5];
    const float* Wv  = (const float*)d_in[6];
    const float* bv  = (const float*)d_in[7];
    const float* Wo  = (const float*)d_in[8];
    const float* bo  = (const float*)d_in[9];
    const float* g0  = (const float*)d_in[10];
    const float* be0 = (const float*)d_in[11];
    const float* g1  = (const float*)d_in[12];
    const float* be1 = (const float*)d_in[13];
    float* out = (float*)d_out;

    const size_t NQK = (size_t)8 * 1024 * 512;  // 4M elems
    bf16* ws   = (bf16*)d_ws;
    bf16* pQh  = ws;                 // [b,h,n,d]
    bf16* pKh  = pQh + NQK;          // [b,h,m,d]
    bf16* pVhT = pKh + NQK;          // [b,h,d,m]
    bf16* pOc  = pVhT + NQK;         // attn out [b,n,512] (workspace!)

    gemm_qkv<<<dim3(64, 12), 256, 0, stream>>>(Q, K, Wq, Wk, Wv, bq, bk, bv, pQh, pKh, pVhT);
    attn_mfma<<<1024, 256, 0, stream>>>(pQh, pKh, pVhT, pOc);
    gemm_fo_ln1<<<256, 512, 0, stream>>>(pOc, Wo, g0, be0, bo, g1, be1, out);
}